// Round 6
// baseline (2952.448 us; speedup 1.0000x reference)
//
#include <hip/hip_runtime.h>
#include <math.h>

#define NN 100000
#define NE 1600000
#define HID 128
#define INCH 256
#define OUTC 40
#define NLAYERS 8
#define NBUCK 391   // ceil(NN/256)
#define EPB 4096
#define CAP 6144

typedef __attribute__((ext_vector_type(8))) short bf16x8;
typedef __attribute__((ext_vector_type(4))) float f32x4;

static __device__ inline unsigned short f2bf(float f) {
  unsigned u = __float_as_uint(f);
  unsigned r = (u + 0x7fff + ((u >> 16) & 1)) >> 16;
  return (unsigned short)r;
}
static __device__ inline float bflo(unsigned u) { return __uint_as_float(u << 16); }
static __device__ inline float bfhi(unsigned u) { return __uint_as_float(u & 0xffff0000u); }

// Feature buffers are slice-major: addr(buf,n,ch) = ((ch>>4)*NN + n)*16 + (ch&15)

// ---------------- preprocessing ----------------

static __global__ void k_zero(int* __restrict__ cnt, int* __restrict__ bcnt) {
  int i = blockIdx.x * 256 + threadIdx.x;
  if (i < NN) cnt[i] = 0;
  if (i < NBUCK) bcnt[i] = 0;
}

// per-edge: global cnt hist (for dinv/offs) + LDS bucket hist
static __global__ __launch_bounds__(256) void k_bcnt(const int* __restrict__ ei,
                                                     int* __restrict__ cnt,
                                                     int* __restrict__ bcnt) {
  __shared__ int lh[512];
  int t = threadIdx.x;
  for (int i = t; i < 512; i += 256) lh[i] = 0;
  __syncthreads();
  int e0 = blockIdx.x * EPB;
  for (int k = t; k < EPB; k += 256) {
    int e = e0 + k;
    if (e < NE) {
      int d = ei[NE + e];
      atomicAdd(&cnt[d], 1);
      atomicAdd(&lh[d >> 8], 1);
    }
  }
  __syncthreads();
  for (int i = t; i < NBUCK; i += 256)
    if (lh[i]) atomicAdd(&bcnt[i], lh[i]);
}

static __global__ void k_dinv(const int* __restrict__ cnt, float* __restrict__ dinv,
                              int* __restrict__ offs) {
  int i = blockIdx.x * 256 + threadIdx.x;
  if (i < NN) dinv[i] = rsqrtf((float)(cnt[i] + 1));
  if (blockIdx.x == 0 && threadIdx.x == 0) offs[NN] = NE;
}

static __global__ void k_scan1(const int* __restrict__ cnt, int* __restrict__ bsum) {
  __shared__ int sd[256];
  int t = threadIdx.x;
  int gid = blockIdx.x * 256 + t;
  sd[t] = (gid < NN) ? cnt[gid] : 0;
  __syncthreads();
  for (int s = 128; s > 0; s >>= 1) {
    if (t < s) sd[t] += sd[t + s];
    __syncthreads();
  }
  if (t == 0) bsum[blockIdx.x] = sd[0];
}

static __global__ void k_scan2(int* __restrict__ bsum, int nb) {
  __shared__ int sd[512];
  int t = threadIdx.x;
  sd[t] = (t < nb) ? bsum[t] : 0;
  __syncthreads();
  for (int d = 1; d < 512; d <<= 1) {
    int v = (t >= d) ? sd[t - d] : 0;
    __syncthreads();
    sd[t] += v;
    __syncthreads();
  }
  if (t < nb) bsum[t] = sd[t];
}

static __global__ void k_scan3(const int* __restrict__ cnt, const int* __restrict__ bsum,
                               int* __restrict__ offs, int* __restrict__ cursor) {
  __shared__ int sd[256];
  int t = threadIdx.x;
  int gid = blockIdx.x * 256 + t;
  int v = (gid < NN) ? cnt[gid] : 0;
  sd[t] = v;
  __syncthreads();
  for (int d = 1; d < 256; d <<= 1) {
    int u = (t >= d) ? sd[t - d] : 0;
    __syncthreads();
    sd[t] += u;
    __syncthreads();
  }
  int base = (blockIdx.x > 0) ? bsum[blockIdx.x - 1] : 0;
  int excl = base + sd[t] - v;
  if (gid < NN) { offs[gid] = excl; cursor[gid] = excl; }
}

static __global__ void k_bscan(const int* __restrict__ bcnt, int* __restrict__ boffs,
                               int* __restrict__ bcur) {
  __shared__ int sd[512];
  int t = threadIdx.x;
  sd[t] = (t < NBUCK) ? bcnt[t] : 0;
  __syncthreads();
  for (int d = 1; d < 512; d <<= 1) {
    int v = (t >= d) ? sd[t - d] : 0;
    __syncthreads();
    sd[t] += v;
    __syncthreads();
  }
  if (t < NBUCK) {
    boffs[t + 1] = sd[t];
    bcur[t] = sd[t] - bcnt[t];
  }
  if (t == 0) boffs[0] = 0;
}

// pass A: bucket-sorted staging scatter (block-aggregated cursor reservation)
static __global__ __launch_bounds__(256) void k_passA(const int* __restrict__ ei,
                                                      int* __restrict__ bcur,
                                                      int2* __restrict__ stage) {
  __shared__ int lh[512], lbase[512], lcur[512];
  int t = threadIdx.x;
  int e0 = blockIdx.x * EPB;
  for (int i = t; i < 512; i += 256) lh[i] = 0;
  __syncthreads();
  for (int k = t; k < EPB; k += 256) {
    int e = e0 + k;
    if (e < NE) atomicAdd(&lh[ei[NE + e] >> 8], 1);
  }
  __syncthreads();
  for (int i = t; i < NBUCK; i += 256) {
    int c = lh[i];
    lbase[i] = c ? atomicAdd(&bcur[i], c) : 0;
    lcur[i] = 0;
  }
  __syncthreads();
  for (int k = t; k < EPB; k += 256) {
    int e = e0 + k;
    if (e < NE) {
      int s = ei[e], d = ei[NE + e];
      int bu = d >> 8;
      int r = atomicAdd(&lcur[bu], 1);
      stage[lbase[bu] + r] = make_int2(s, d);
    }
  }
}

// pass B: per-bucket LDS scatter -> sequential CSR writes (+ weight compute)
static __global__ __launch_bounds__(256) void k_passB(
    const int2* __restrict__ stage, const int* __restrict__ boffs,
    const int* __restrict__ offs, const float* __restrict__ dinv,
    int* __restrict__ cursor, int2* __restrict__ edata) {
  __shared__ int2 lbuf[CAP];
  __shared__ int lcur[256];
  int b = blockIdx.x, t = threadIdx.x;
  int sb = boffs[b], se = boffs[b + 1];
  int cntb = se - sb;
  int nb0 = b << 8;
  int off0 = offs[nb0];
  if (cntb <= CAP) {
    if (t < 256 && nb0 + t < NN) lcur[t] = offs[nb0 + t] - off0;
    __syncthreads();
    for (int k = t; k < cntb; k += 256) {
      int2 sd_ = stage[sb + k];
      float w = dinv[sd_.x] * dinv[sd_.y];
      int p = atomicAdd(&lcur[sd_.y - nb0], 1);
      lbuf[p] = make_int2(sd_.x, __float_as_int(w));
    }
    __syncthreads();
    for (int k = t; k < cntb; k += 256) edata[off0 + k] = lbuf[k];
  } else {  // fallback (never expected for this graph)
    for (int k = t; k < cntb; k += 256) {
      int2 sd_ = stage[sb + k];
      float w = dinv[sd_.x] * dinv[sd_.y];
      int p = atomicAdd(&cursor[sd_.y], 1);
      edata[p] = make_int2(sd_.x, __float_as_int(w));
    }
  }
}

// ---------------- weight conversion ----------------
static __global__ void k_cvtw(const float* __restrict__ W, unsigned short* __restrict__ Wt,
                              int K) {
  int idx = blockIdx.x * 256 + threadIdx.x;
  if (idx < K * HID) {
    int k = idx >> 7, n = idx & 127;
    Wt[(size_t)n * K + k] = f2bf(W[idx]);
  }
}

static __global__ void k_cvtw8(const float* __restrict__ W, unsigned short* __restrict__ Wt) {
  int idx = blockIdx.x * 256 + threadIdx.x;
  if (idx < NLAYERS * HID * HID) {
    int l = idx >> 14, rem = idx & 16383;
    int k = rem >> 7, n = rem & 127;
    Wt[(size_t)l * HID * HID + n * HID + k] = f2bf(W[idx]);
  }
}

static __global__ void k_cvtw2(const float* __restrict__ W2, unsigned short* __restrict__ Wt2) {
  int idx = blockIdx.x * 256 + threadIdx.x;
  if (idx < 48 * HID) {
    int n = idx >> 7, k = idx & 127;
    Wt2[idx] = (n < OUTC) ? f2bf(W2[(size_t)k * OUTC + n]) : 0;
  }
}

// ---------------- lin1: C16(slice-major) = bf16(relu(A32 @ W + bias)) ----------------
__global__ __launch_bounds__(256, 2) void k_lin1(
    const float* __restrict__ A32, const unsigned short* __restrict__ Wt16,
    const float* __restrict__ bias, unsigned short* __restrict__ C16, int M) {
  constexpr int K = INCH, KS = K / 32, CT = 4;
  const int lane = threadIdx.x & 63;
  const int wid = threadIdx.x >> 6;
  const int rowblk = wid >> 1;
  const int colbase = (wid & 1) << 6;
  const int j = lane & 15, g = lane >> 4;

  bf16x8 bfrag[CT][KS];
#pragma unroll
  for (int c = 0; c < CT; ++c)
#pragma unroll
    for (int s = 0; s < KS; ++s)
      bfrag[c][s] =
          *(const bf16x8*)(Wt16 + (size_t)(colbase + 16 * c + j) * K + 32 * s + 8 * g);

  const int wrow0 = blockIdx.x * 128 + rowblk * 64;
  const f32x4 zero = {0.f, 0.f, 0.f, 0.f};
#pragma unroll 1
  for (int t = 0; t < 4; ++t) {
    const int row0 = wrow0 + 16 * t;
    int rl = row0 + j;
    if (rl >= M) rl = M - 1;
    bf16x8 af[KS];
#pragma unroll
    for (int s = 0; s < KS; ++s) {
      const float* p = A32 + (size_t)rl * K + 32 * s + 8 * g;
      float4 u0 = *(const float4*)p;
      float4 u1 = *(const float4*)(p + 4);
      bf16x8 v;
      v[0] = (short)f2bf(u0.x); v[1] = (short)f2bf(u0.y);
      v[2] = (short)f2bf(u0.z); v[3] = (short)f2bf(u0.w);
      v[4] = (short)f2bf(u1.x); v[5] = (short)f2bf(u1.y);
      v[6] = (short)f2bf(u1.z); v[7] = (short)f2bf(u1.w);
      af[s] = v;
    }
    f32x4 acc[CT];
#pragma unroll
    for (int c = 0; c < CT; ++c) acc[c] = zero;
#pragma unroll
    for (int s = 0; s < KS; ++s)
#pragma unroll
      for (int c = 0; c < CT; ++c)
        acc[c] = __builtin_amdgcn_mfma_f32_16x16x32_bf16(af[s], bfrag[c][s], acc[c], 0, 0, 0);

#pragma unroll
    for (int i = 0; i < 4; ++i) {
      const int rr = row0 + 4 * g + i;
      if (rr >= M) continue;
#pragma unroll
      for (int c = 0; c < CT; ++c) {
        const int col = colbase + 16 * c + j;
        float z = fmaxf(acc[c][i] + bias[col], 0.f);
        C16[((size_t)(col >> 4) * NN + rr) * 16 + (col & 15)] = f2bf(z);
      }
    }
  }
}

// ---------------- layer GEMM (slice-major in/out) ----------------
__global__ __launch_bounds__(256, 2) void k_mgemm1(
    const unsigned short* __restrict__ A16, const unsigned short* __restrict__ Wt16,
    float beta, unsigned short* __restrict__ C16, int M) {
  constexpr int KS = 4, CT = 4;
  const int lane = threadIdx.x & 63;
  const int wid = threadIdx.x >> 6;
  const int rowblk = wid >> 1;
  const int colbase = (wid & 1) << 6;
  const int j = lane & 15, g = lane >> 4;

  bf16x8 bfrag[CT][KS];
#pragma unroll
  for (int c = 0; c < CT; ++c)
#pragma unroll
    for (int s = 0; s < KS; ++s)
      bfrag[c][s] =
          *(const bf16x8*)(Wt16 + (size_t)(colbase + 16 * c + j) * HID + 32 * s + 8 * g);

  const int wrow0 = blockIdx.x * 128 + rowblk * 64;

  bf16x8 af[4][KS];
#pragma unroll
  for (int t = 0; t < 4; ++t) {
    int rl = wrow0 + 16 * t + j;
    if (rl >= M) rl = M - 1;
#pragma unroll
    for (int s = 0; s < KS; ++s)
      af[t][s] = *(const bf16x8*)(A16 + ((size_t)(2 * s + (g >> 1)) * NN + rl) * 16 +
                                  8 * (g & 1));
  }

  const f32x4 zero = {0.f, 0.f, 0.f, 0.f};
  const float ob = 1.f - beta;
#pragma unroll
  for (int t = 0; t < 4; ++t) {
    const int row0 = wrow0 + 16 * t;
    f32x4 acc[CT];
#pragma unroll
    for (int c = 0; c < CT; ++c) acc[c] = zero;
#pragma unroll
    for (int s = 0; s < KS; ++s)
#pragma unroll
      for (int c = 0; c < CT; ++c)
        acc[c] = __builtin_amdgcn_mfma_f32_16x16x32_bf16(af[t][s], bfrag[c][s], acc[c], 0, 0, 0);

#pragma unroll
    for (int i = 0; i < 4; ++i) {
      const int rr = row0 + 4 * g + i;
      if (rr >= M) continue;
#pragma unroll
      for (int c = 0; c < CT; ++c) {
        const int col = colbase + 16 * c + j;
        size_t adr = ((size_t)(col >> 4) * NN + rr) * 16 + (col & 15);
        float hc = bflo(A16[adr]);
        float z = fmaxf(fmaf(beta, acc[c][i], ob * hc), 0.f);
        C16[adr] = f2bf(z);
      }
    }
  }
}

// ---------------- fused lin2 + log_softmax (slice-major input) ----------------
static __global__ __launch_bounds__(256) void k_mlin2(
    const unsigned short* __restrict__ h16, const unsigned short* __restrict__ Wt2,
    const float* __restrict__ b2, float* __restrict__ out) {
  const int lane = threadIdx.x & 63;
  const int wid = threadIdx.x >> 6;
  const int j = lane & 15, g = lane >> 4;

  bf16x8 bfrag[3][4];
#pragma unroll
  for (int c = 0; c < 3; ++c)
#pragma unroll
    for (int s = 0; s < 4; ++s)
      bfrag[c][s] = *(const bf16x8*)(Wt2 + (size_t)(16 * c + j) * HID + 32 * s + 8 * g);

  float bb[3];
#pragma unroll
  for (int c = 0; c < 3; ++c) {
    int col = 16 * c + j;
    bb[c] = (col < OUTC) ? b2[col] : -1e30f;
  }

  const int wrow0 = blockIdx.x * 256 + wid * 64;
  const f32x4 zero = {0.f, 0.f, 0.f, 0.f};
#pragma unroll 1
  for (int t = 0; t < 4; ++t) {
    const int row0 = wrow0 + 16 * t;
    int rl = row0 + j;
    if (rl >= NN) rl = NN - 1;
    bf16x8 af[4];
#pragma unroll
    for (int s = 0; s < 4; ++s)
      af[s] = *(const bf16x8*)(h16 + ((size_t)(2 * s + (g >> 1)) * NN + rl) * 16 +
                               8 * (g & 1));
    f32x4 acc[3] = {zero, zero, zero};
#pragma unroll
    for (int s = 0; s < 4; ++s)
#pragma unroll
      for (int c = 0; c < 3; ++c)
        acc[c] = __builtin_amdgcn_mfma_f32_16x16x32_bf16(af[s], bfrag[c][s], acc[c], 0, 0, 0);

#pragma unroll
    for (int i = 0; i < 4; ++i) {
      const int rr = row0 + 4 * g + i;
      float z0 = acc[0][i] + bb[0];
      float z1 = acc[1][i] + bb[1];
      float z2 = acc[2][i] + bb[2];
      float m = fmaxf(fmaxf(z0, z1), z2);
      m = fmaxf(m, __shfl_xor(m, 1));
      m = fmaxf(m, __shfl_xor(m, 2));
      m = fmaxf(m, __shfl_xor(m, 4));
      m = fmaxf(m, __shfl_xor(m, 8));
      float sum = __expf(z0 - m) + __expf(z1 - m) + __expf(z2 - m);
      sum += __shfl_xor(sum, 1);
      sum += __shfl_xor(sum, 2);
      sum += __shfl_xor(sum, 4);
      sum += __shfl_xor(sum, 8);
      float ls = m + logf(sum);
      if (rr < NN) {
        out[(size_t)rr * OUTC + j] = z0 - ls;
        out[(size_t)rr * OUTC + 16 + j] = z1 - ls;
        if (j < 8) out[(size_t)rr * OUTC + 32 + j] = z2 - ls;
      }
    }
  }
}

// ---------------- aggregation: slice-sharded, XCD-pinned ----------------
// grid = nodegroups x 8 slices; slice = blockIdx&7 (round-robin -> same XCD).
// Block = 4 waves, one node/wave. Wave = 32 edge-slots x 2 lanes x 8ch (16B).
static __global__ __launch_bounds__(256) void k_agg(
    const unsigned short* __restrict__ h16, const unsigned short* __restrict__ x016,
    const float* __restrict__ dinv, const int* __restrict__ offs,
    const int2* __restrict__ edata, unsigned short* __restrict__ hc16) {
  const int s = blockIdx.x & 7;
  const int ng = blockIdx.x >> 3;
  const int wid = threadIdx.x >> 6;
  const int n = ng * 4 + wid;
  if (n >= NN) return;
  const int lane = threadIdx.x & 63;
  const int slot = lane >> 1, half = lane & 1;
  const unsigned short* __restrict__ hs = h16 + (size_t)s * NN * 16;

  int b = offs[n], e = offs[n + 1];
  float acc[8];
#pragma unroll
  for (int q = 0; q < 8; ++q) acc[q] = 0.f;

#define ACC8S(PTR, W)                                        \
  {                                                          \
    const uint4 v = *(const uint4*)(PTR);                    \
    acc[0] = fmaf((W), bflo(v.x), acc[0]);                   \
    acc[1] = fmaf((W), bfhi(v.x), acc[1]);                   \
    acc[2] = fmaf((W), bflo(v.y), acc[2]);                   \
    acc[3] = fmaf((W), bfhi(v.y), acc[3]);                   \
    acc[4] = fmaf((W), bflo(v.z), acc[4]);                   \
    acc[5] = fmaf((W), bfhi(v.z), acc[5]);                   \
    acc[6] = fmaf((W), bflo(v.w), acc[6]);                   \
    acc[7] = fmaf((W), bfhi(v.w), acc[7]);                   \
  }

  if (slot == 0) {  // self loop
    float dn = dinv[n];
    ACC8S(hs + (size_t)n * 16 + half * 8, dn * dn);
  }
  for (int i = b + slot; i < e; i += 32) {
    int2 ed = edata[i];
    float w = __int_as_float(ed.y);
    ACC8S(hs + (size_t)ed.x * 16 + half * 8, w);
  }
#undef ACC8S

#pragma unroll
  for (int q = 0; q < 8; ++q) {
    acc[q] += __shfl_xor(acc[q], 2);
    acc[q] += __shfl_xor(acc[q], 4);
    acc[q] += __shfl_xor(acc[q], 8);
    acc[q] += __shfl_xor(acc[q], 16);
    acc[q] += __shfl_xor(acc[q], 32);
  }

  if (lane < 2) {
    size_t base = ((size_t)s * NN + n) * 16 + half * 8;
    const uint4 xv = *(const uint4*)(x016 + base);
    float o[8];
    o[0] = 0.5f * acc[0] + 0.5f * bflo(xv.x);
    o[1] = 0.5f * acc[1] + 0.5f * bfhi(xv.x);
    o[2] = 0.5f * acc[2] + 0.5f * bflo(xv.y);
    o[3] = 0.5f * acc[3] + 0.5f * bfhi(xv.y);
    o[4] = 0.5f * acc[4] + 0.5f * bflo(xv.z);
    o[5] = 0.5f * acc[5] + 0.5f * bfhi(xv.z);
    o[6] = 0.5f * acc[6] + 0.5f * bflo(xv.w);
    o[7] = 0.5f * acc[7] + 0.5f * bfhi(xv.w);
    unsigned short q[8];
#pragma unroll
    for (int t = 0; t < 8; ++t) q[t] = f2bf(o[t]);
    *(uint4*)(hc16 + base) = *(const uint4*)&q[0];
  }
}

// ---------------- host ----------------
extern "C" void kernel_launch(void* const* d_in, const int* in_sizes, int n_in,
                              void* d_out, int out_size, void* d_ws, size_t ws_size,
                              hipStream_t stream) {
  const float* x  = (const float*)d_in[0];
  const int*   ei = (const int*)d_in[1];
  const float* w1 = (const float*)d_in[2];
  const float* b1 = (const float*)d_in[3];
  const float* cw = (const float*)d_in[4];
  const float* w2 = (const float*)d_in[5];
  const float* b2 = (const float*)d_in[6];
  float* out = (float*)d_out;

  char* ws = (char*)d_ws;
  size_t o = 0;
  auto carve = [&](size_t bytes) {
    void* p = ws + o;
    o = (o + bytes + 255) & ~(size_t)255;
    return p;
  };
  int*   cnt    = (int*)carve((size_t)NN * 4);
  float* dinv   = (float*)carve((size_t)NN * 4);
  int*   offs   = (int*)carve((size_t)(NN + 1) * 4);
  int*   cursor = (int*)carve((size_t)NN * 4);
  int*   bsum   = (int*)carve(512 * 4);
  int*   bcnt   = (int*)carve((size_t)NBUCK * 4);
  int*   boffs  = (int*)carve((size_t)(NBUCK + 1) * 4);
  int*   bcur   = (int*)carve((size_t)NBUCK * 4);
  int2*  stage  = (int2*)carve((size_t)NE * 8);
  int2*  edata  = (int2*)carve((size_t)NE * 8);
  unsigned short* x016  = (unsigned short*)carve((size_t)NN * HID * 2);
  unsigned short* hb16  = (unsigned short*)carve((size_t)NN * HID * 2);
  unsigned short* hcb16 = (unsigned short*)carve((size_t)NN * HID * 2);
  unsigned short* wt1   = (unsigned short*)carve((size_t)INCH * HID * 2);
  unsigned short* wtl   = (unsigned short*)carve((size_t)NLAYERS * HID * HID * 2);
  unsigned short* wt2   = (unsigned short*)carve((size_t)48 * HID * 2);
  (void)ws_size; (void)in_sizes; (void)n_in; (void)out_size;

  const int TB = 256;
  const int gN = (NN + TB - 1) / TB;     // 391
  const int gEB = (NE + EPB - 1) / EPB;  // 391

  k_zero<<<gN, TB, 0, stream>>>(cnt, bcnt);
  k_bcnt<<<gEB, TB, 0, stream>>>(ei, cnt, bcnt);
  k_dinv<<<gN, TB, 0, stream>>>(cnt, dinv, offs);
  k_scan1<<<gN, TB, 0, stream>>>(cnt, bsum);
  k_scan2<<<1, 512, 0, stream>>>(bsum, gN);
  k_scan3<<<gN, TB, 0, stream>>>(cnt, bsum, offs, cursor);
  k_bscan<<<1, 512, 0, stream>>>(bcnt, boffs, bcur);
  k_passA<<<gEB, TB, 0, stream>>>(ei, bcur, stage);
  k_passB<<<NBUCK, TB, 0, stream>>>(stage, boffs, offs, dinv, cursor, edata);

  k_cvtw<<<(INCH * HID + 255) / 256, 256, 0, stream>>>(w1, wt1, INCH);
  k_cvtw8<<<(NLAYERS * HID * HID + 255) / 256, 256, 0, stream>>>(cw, wtl);
  k_cvtw2<<<(48 * HID + 255) / 256, 256, 0, stream>>>(w2, wt2);

  k_lin1<<<(NN + 127) / 128, 256, 0, stream>>>(x, wt1, b1, x016, NN);

  const unsigned short* hin = x016;
  const int gA = ((NN + 3) / 4) * 8;  // nodegroups x 8 slices
  for (int l = 0; l < NLAYERS; ++l) {
    float beta = logf(1.0f / (float)(l + 1) + 1.0f);
    k_agg<<<gA, 256, 0, stream>>>(hin, x016, dinv, offs, edata, hcb16);
    k_mgemm1<<<(NN + 127) / 128, 256, 0, stream>>>(
        hcb16, wtl + (size_t)l * HID * HID, beta, hb16, NN);
    hin = hb16;
  }
  k_mlin2<<<(NN + 255) / 256, 256, 0, stream>>>(hb16, wt2, b2, out);
}

// Round 7
// 1039.293 us; speedup vs baseline: 2.8408x; 2.8408x over previous
//
#include <hip/hip_runtime.h>
#include <math.h>

#define NN 100000
#define NE 1600000
#define HID 128
#define INCH 256
#define OUTC 40
#define NLAYERS 8
#define NBUCK 391   // ceil(NN/256)
#define EPB 4096
#define CAP 6144

typedef __attribute__((ext_vector_type(8))) short bf16x8;
typedef __attribute__((ext_vector_type(4))) float f32x4;

static __device__ inline unsigned short f2bf(float f) {
  unsigned u = __float_as_uint(f);
  unsigned r = (u + 0x7fff + ((u >> 16) & 1)) >> 16;
  return (unsigned short)r;
}
static __device__ inline float bflo(unsigned u) { return __uint_as_float(u << 16); }
static __device__ inline float bfhi(unsigned u) { return __uint_as_float(u & 0xffff0000u); }

// ---------------- preprocessing ----------------

static __global__ void k_zero(int* __restrict__ cnt, int* __restrict__ bcnt) {
  int i = blockIdx.x * 256 + threadIdx.x;
  if (i < NN) cnt[i] = 0;
  if (i < NBUCK) bcnt[i] = 0;
}

static __global__ __launch_bounds__(256) void k_bcnt(const int* __restrict__ ei,
                                                     int* __restrict__ cnt,
                                                     int* __restrict__ bcnt) {
  __shared__ int lh[512];
  int t = threadIdx.x;
  for (int i = t; i < 512; i += 256) lh[i] = 0;
  __syncthreads();
  int e0 = blockIdx.x * EPB;
  for (int k = t; k < EPB; k += 256) {
    int e = e0 + k;
    if (e < NE) {
      int d = ei[NE + e];
      atomicAdd(&cnt[d], 1);
      atomicAdd(&lh[d >> 8], 1);
    }
  }
  __syncthreads();
  for (int i = t; i < NBUCK; i += 256)
    if (lh[i]) atomicAdd(&bcnt[i], lh[i]);
}

static __global__ void k_dinv(const int* __restrict__ cnt, float* __restrict__ dinv,
                              int* __restrict__ offs) {
  int i = blockIdx.x * 256 + threadIdx.x;
  if (i < NN) dinv[i] = rsqrtf((float)(cnt[i] + 1));
  if (blockIdx.x == 0 && threadIdx.x == 0) offs[NN] = NE;
}

static __global__ void k_scan1(const int* __restrict__ cnt, int* __restrict__ bsum) {
  __shared__ int sd[256];
  int t = threadIdx.x;
  int gid = blockIdx.x * 256 + t;
  sd[t] = (gid < NN) ? cnt[gid] : 0;
  __syncthreads();
  for (int s = 128; s > 0; s >>= 1) {
    if (t < s) sd[t] += sd[t + s];
    __syncthreads();
  }
  if (t == 0) bsum[blockIdx.x] = sd[0];
}

static __global__ void k_scan2(int* __restrict__ bsum, int nb) {
  __shared__ int sd[512];
  int t = threadIdx.x;
  sd[t] = (t < nb) ? bsum[t] : 0;
  __syncthreads();
  for (int d = 1; d < 512; d <<= 1) {
    int v = (t >= d) ? sd[t - d] : 0;
    __syncthreads();
    sd[t] += v;
    __syncthreads();
  }
  if (t < nb) bsum[t] = sd[t];
}

static __global__ void k_scan3(const int* __restrict__ cnt, const int* __restrict__ bsum,
                               int* __restrict__ offs, int* __restrict__ cursor) {
  __shared__ int sd[256];
  int t = threadIdx.x;
  int gid = blockIdx.x * 256 + t;
  int v = (gid < NN) ? cnt[gid] : 0;
  sd[t] = v;
  __syncthreads();
  for (int d = 1; d < 256; d <<= 1) {
    int u = (t >= d) ? sd[t - d] : 0;
    __syncthreads();
    sd[t] += u;
    __syncthreads();
  }
  int base = (blockIdx.x > 0) ? bsum[blockIdx.x - 1] : 0;
  int excl = base + sd[t] - v;
  if (gid < NN) { offs[gid] = excl; cursor[gid] = excl; }
}

static __global__ void k_bscan(const int* __restrict__ bcnt, int* __restrict__ boffs,
                               int* __restrict__ bcur) {
  __shared__ int sd[512];
  int t = threadIdx.x;
  sd[t] = (t < NBUCK) ? bcnt[t] : 0;
  __syncthreads();
  for (int d = 1; d < 512; d <<= 1) {
    int v = (t >= d) ? sd[t - d] : 0;
    __syncthreads();
    sd[t] += v;
    __syncthreads();
  }
  if (t < NBUCK) {
    boffs[t + 1] = sd[t];
    bcur[t] = sd[t] - bcnt[t];
  }
  if (t == 0) boffs[0] = 0;
}

static __global__ __launch_bounds__(256) void k_passA(const int* __restrict__ ei,
                                                      int* __restrict__ bcur,
                                                      int2* __restrict__ stage) {
  __shared__ int lh[512], lbase[512], lcur[512];
  int t = threadIdx.x;
  int e0 = blockIdx.x * EPB;
  for (int i = t; i < 512; i += 256) lh[i] = 0;
  __syncthreads();
  for (int k = t; k < EPB; k += 256) {
    int e = e0 + k;
    if (e < NE) atomicAdd(&lh[ei[NE + e] >> 8], 1);
  }
  __syncthreads();
  for (int i = t; i < NBUCK; i += 256) {
    int c = lh[i];
    lbase[i] = c ? atomicAdd(&bcur[i], c) : 0;
    lcur[i] = 0;
  }
  __syncthreads();
  for (int k = t; k < EPB; k += 256) {
    int e = e0 + k;
    if (e < NE) {
      int s = ei[e], d = ei[NE + e];
      int bu = d >> 8;
      int r = atomicAdd(&lcur[bu], 1);
      stage[lbase[bu] + r] = make_int2(s, d);
    }
  }
}

static __global__ __launch_bounds__(256) void k_passB(
    const int2* __restrict__ stage, const int* __restrict__ boffs,
    const int* __restrict__ offs, const float* __restrict__ dinv,
    int* __restrict__ cursor, int2* __restrict__ edata) {
  __shared__ int2 lbuf[CAP];
  __shared__ int lcur[256];
  int b = blockIdx.x, t = threadIdx.x;
  int sb = boffs[b], se = boffs[b + 1];
  int cntb = se - sb;
  int nb0 = b << 8;
  int off0 = offs[nb0];
  if (cntb <= CAP) {
    if (t < 256 && nb0 + t < NN) lcur[t] = offs[nb0 + t] - off0;
    __syncthreads();
    for (int k = t; k < cntb; k += 256) {
      int2 sd_ = stage[sb + k];
      float w = dinv[sd_.x] * dinv[sd_.y];
      int p = atomicAdd(&lcur[sd_.y - nb0], 1);
      lbuf[p] = make_int2(sd_.x, __float_as_int(w));
    }
    __syncthreads();
    for (int k = t; k < cntb; k += 256) edata[off0 + k] = lbuf[k];
  } else {
    for (int k = t; k < cntb; k += 256) {
      int2 sd_ = stage[sb + k];
      float w = dinv[sd_.x] * dinv[sd_.y];
      int p = atomicAdd(&cursor[sd_.y], 1);
      edata[p] = make_int2(sd_.x, __float_as_int(w));
    }
  }
}

// ---------------- weight conversion ----------------
static __global__ void k_cvtw(const float* __restrict__ W, unsigned short* __restrict__ Wt,
                              int K) {
  int idx = blockIdx.x * 256 + threadIdx.x;
  if (idx < K * HID) {
    int k = idx >> 7, n = idx & 127;
    Wt[(size_t)n * K + k] = f2bf(W[idx]);
  }
}

static __global__ void k_cvtw8(const float* __restrict__ W, unsigned short* __restrict__ Wt) {
  int idx = blockIdx.x * 256 + threadIdx.x;
  if (idx < NLAYERS * HID * HID) {
    int l = idx >> 14, rem = idx & 16383;
    int k = rem >> 7, n = rem & 127;
    Wt[(size_t)l * HID * HID + n * HID + k] = f2bf(W[idx]);
  }
}

static __global__ void k_cvtw2(const float* __restrict__ W2, unsigned short* __restrict__ Wt2) {
  int idx = blockIdx.x * 256 + threadIdx.x;
  if (idx < 48 * HID) {
    int n = idx >> 7, k = idx & 127;
    Wt2[idx] = (n < OUTC) ? f2bf(W2[(size_t)k * OUTC + n]) : 0;
  }
}

// ---------------- lin1: C16[M x 128] = bf16(relu(A32[M x 256] @ W + bias)) ----------------
// wave = 16 rows x 64 cols; block = 32 rows; K chunked 2 x 128. grid = M/32.
__global__ __launch_bounds__(256, 4) void k_lin1(
    const float* __restrict__ A32, const unsigned short* __restrict__ Wt16,
    const float* __restrict__ bias, unsigned short* __restrict__ C16, int M) {
  const int lane = threadIdx.x & 63;
  const int wid = threadIdx.x >> 6;
  const int row0 = blockIdx.x * 32 + (wid >> 1) * 16;
  const int colbase = (wid & 1) << 6;
  const int j = lane & 15, g = lane >> 4;

  int rl = row0 + j;
  if (rl >= M) rl = M - 1;

  f32x4 acc[4];
  const f32x4 zero = {0.f, 0.f, 0.f, 0.f};
#pragma unroll
  for (int c = 0; c < 4; ++c) acc[c] = zero;

#pragma unroll
  for (int kc = 0; kc < 2; ++kc) {
    bf16x8 bfrag[4][4];
#pragma unroll
    for (int c = 0; c < 4; ++c)
#pragma unroll
      for (int s = 0; s < 4; ++s)
        bfrag[c][s] = *(const bf16x8*)(Wt16 + (size_t)(colbase + 16 * c + j) * INCH +
                                       kc * 128 + 32 * s + 8 * g);
    bf16x8 af[4];
#pragma unroll
    for (int s = 0; s < 4; ++s) {
      const float* p = A32 + (size_t)rl * INCH + kc * 128 + 32 * s + 8 * g;
      float4 u0 = *(const float4*)p;
      float4 u1 = *(const float4*)(p + 4);
      bf16x8 v;
      v[0] = (short)f2bf(u0.x); v[1] = (short)f2bf(u0.y);
      v[2] = (short)f2bf(u0.z); v[3] = (short)f2bf(u0.w);
      v[4] = (short)f2bf(u1.x); v[5] = (short)f2bf(u1.y);
      v[6] = (short)f2bf(u1.z); v[7] = (short)f2bf(u1.w);
      af[s] = v;
    }
#pragma unroll
    for (int s = 0; s < 4; ++s)
#pragma unroll
      for (int c = 0; c < 4; ++c)
        acc[c] = __builtin_amdgcn_mfma_f32_16x16x32_bf16(af[s], bfrag[c][s], acc[c], 0, 0, 0);
  }

#pragma unroll
  for (int i = 0; i < 4; ++i) {
    const int rr = row0 + 4 * g + i;
    if (rr >= M) continue;
#pragma unroll
    for (int c = 0; c < 4; ++c) {
      const int col = colbase + 16 * c + j;
      float z = fmaxf(acc[c][i] + bias[col], 0.f);
      C16[(size_t)rr * HID + col] = f2bf(z);
    }
  }
}

// ---------------- layer GEMM: C16 = bf16(relu((1-beta)*A16 + beta*(A16 @ W))) ----------------
// wave = 16 rows x 64 cols; block = 32 rows; grid = M/32.
__global__ __launch_bounds__(256, 4) void k_mgemm1(
    const unsigned short* __restrict__ A16, const unsigned short* __restrict__ Wt16,
    float beta, unsigned short* __restrict__ C16, int M) {
  const int lane = threadIdx.x & 63;
  const int wid = threadIdx.x >> 6;
  const int row0 = blockIdx.x * 32 + (wid >> 1) * 16;
  const int colbase = (wid & 1) << 6;
  const int j = lane & 15, g = lane >> 4;

  bf16x8 bfrag[4][4];
#pragma unroll
  for (int c = 0; c < 4; ++c)
#pragma unroll
    for (int s = 0; s < 4; ++s)
      bfrag[c][s] =
          *(const bf16x8*)(Wt16 + (size_t)(colbase + 16 * c + j) * HID + 32 * s + 8 * g);

  int rl = row0 + j;
  if (rl >= M) rl = M - 1;
  bf16x8 af[4];
#pragma unroll
  for (int s = 0; s < 4; ++s)
    af[s] = *(const bf16x8*)(A16 + (size_t)rl * HID + 32 * s + 8 * g);

  f32x4 acc[4];
  const f32x4 zero = {0.f, 0.f, 0.f, 0.f};
#pragma unroll
  for (int c = 0; c < 4; ++c) acc[c] = zero;
#pragma unroll
  for (int s = 0; s < 4; ++s)
#pragma unroll
    for (int c = 0; c < 4; ++c)
      acc[c] = __builtin_amdgcn_mfma_f32_16x16x32_bf16(af[s], bfrag[c][s], acc[c], 0, 0, 0);

  const float ob = 1.f - beta;
#pragma unroll
  for (int i = 0; i < 4; ++i) {
    const int rr = row0 + 4 * g + i;
    if (rr >= M) continue;
#pragma unroll
    for (int c = 0; c < 4; ++c) {
      const int col = colbase + 16 * c + j;
      float hc = bflo(A16[(size_t)rr * HID + col]);
      float z = fmaxf(fmaf(beta, acc[c][i], ob * hc), 0.f);
      C16[(size_t)rr * HID + col] = f2bf(z);
    }
  }
}

// ---------------- fused lin2 + log_softmax via MFMA ----------------
// wave = 16 rows; block = 64 rows; grid = ceil(M/64).
static __global__ __launch_bounds__(256, 4) void k_mlin2(
    const unsigned short* __restrict__ h16, const unsigned short* __restrict__ Wt2,
    const float* __restrict__ b2, float* __restrict__ out) {
  const int lane = threadIdx.x & 63;
  const int wid = threadIdx.x >> 6;
  const int j = lane & 15, g = lane >> 4;

  bf16x8 bfrag[3][4];
#pragma unroll
  for (int c = 0; c < 3; ++c)
#pragma unroll
    for (int s = 0; s < 4; ++s)
      bfrag[c][s] = *(const bf16x8*)(Wt2 + (size_t)(16 * c + j) * HID + 32 * s + 8 * g);

  float bb[3];
#pragma unroll
  for (int c = 0; c < 3; ++c) {
    int col = 16 * c + j;
    bb[c] = (col < OUTC) ? b2[col] : -1e30f;
  }

  const int row0 = blockIdx.x * 64 + wid * 16;
  int rl = row0 + j;
  if (rl >= NN) rl = NN - 1;
  bf16x8 af[4];
#pragma unroll
  for (int s = 0; s < 4; ++s)
    af[s] = *(const bf16x8*)(h16 + (size_t)rl * HID + 32 * s + 8 * g);

  const f32x4 zero = {0.f, 0.f, 0.f, 0.f};
  f32x4 acc[3] = {zero, zero, zero};
#pragma unroll
  for (int s = 0; s < 4; ++s)
#pragma unroll
    for (int c = 0; c < 3; ++c)
      acc[c] = __builtin_amdgcn_mfma_f32_16x16x32_bf16(af[s], bfrag[c][s], acc[c], 0, 0, 0);

#pragma unroll
  for (int i = 0; i < 4; ++i) {
    const int rr = row0 + 4 * g + i;
    float z0 = acc[0][i] + bb[0];
    float z1 = acc[1][i] + bb[1];
    float z2 = acc[2][i] + bb[2];
    float m = fmaxf(fmaxf(z0, z1), z2);
    m = fmaxf(m, __shfl_xor(m, 1));
    m = fmaxf(m, __shfl_xor(m, 2));
    m = fmaxf(m, __shfl_xor(m, 4));
    m = fmaxf(m, __shfl_xor(m, 8));
    float sum = __expf(z0 - m) + __expf(z1 - m) + __expf(z2 - m);
    sum += __shfl_xor(sum, 1);
    sum += __shfl_xor(sum, 2);
    sum += __shfl_xor(sum, 4);
    sum += __shfl_xor(sum, 8);
    float ls = m + logf(sum);
    if (rr < NN) {
      out[(size_t)rr * OUTC + j] = z0 - ls;
      out[(size_t)rr * OUTC + 16 + j] = z1 - ls;
      if (j < 8) out[(size_t)rr * OUTC + 32 + j] = z2 - ls;
    }
  }
}

// ---------------- aggregation: hc16 = bf16(0.5*(A_hat @ h16) + 0.5*x016) ----------------
// 4 waves/block, one node per wave. Wave: 8 edge-slots x 8 lanes x 16 ch, unroll x2.
static __global__ __launch_bounds__(256) void k_agg(
    const unsigned short* __restrict__ h16, const unsigned short* __restrict__ x016,
    const float* __restrict__ dinv, const int* __restrict__ offs,
    const int2* __restrict__ edata, unsigned short* __restrict__ hc16) {
  int wid = threadIdx.x >> 6;
  int n = blockIdx.x * 4 + wid;
  if (n >= NN) return;
  int lane = threadIdx.x & 63;
  int cg = (lane & 7) * 16;
  int slot = lane >> 3;

  int b = offs[n], e = offs[n + 1];
  float acc[16];
#pragma unroll
  for (int q = 0; q < 16; ++q) acc[q] = 0.f;

#define ACC16(VA, VB, W)                                               \
  {                                                                    \
    acc[0]  = fmaf((W), bflo((VA).x), acc[0]);                         \
    acc[1]  = fmaf((W), bfhi((VA).x), acc[1]);                         \
    acc[2]  = fmaf((W), bflo((VA).y), acc[2]);                         \
    acc[3]  = fmaf((W), bfhi((VA).y), acc[3]);                         \
    acc[4]  = fmaf((W), bflo((VA).z), acc[4]);                         \
    acc[5]  = fmaf((W), bfhi((VA).z), acc[5]);                         \
    acc[6]  = fmaf((W), bflo((VA).w), acc[6]);                         \
    acc[7]  = fmaf((W), bfhi((VA).w), acc[7]);                         \
    acc[8]  = fmaf((W), bflo((VB).x), acc[8]);                         \
    acc[9]  = fmaf((W), bfhi((VB).x), acc[9]);                         \
    acc[10] = fmaf((W), bflo((VB).y), acc[10]);                        \
    acc[11] = fmaf((W), bfhi((VB).y), acc[11]);                        \
    acc[12] = fmaf((W), bflo((VB).z), acc[12]);                        \
    acc[13] = fmaf((W), bfhi((VB).z), acc[13]);                        \
    acc[14] = fmaf((W), bflo((VB).w), acc[14]);                        \
    acc[15] = fmaf((W), bfhi((VB).w), acc[15]);                        \
  }

  if (slot == 0) {
    float dn = dinv[n];
    const unsigned short* p = h16 + (size_t)n * HID + cg;
    uint4 va = *(const uint4*)p, vb = *(const uint4*)(p + 8);
    ACC16(va, vb, dn * dn);
  }
  int i = b + slot;
  for (; i + 8 < e; i += 16) {
    int2 e0 = edata[i], e1 = edata[i + 8];
    const unsigned short* p0 = h16 + (size_t)e0.x * HID + cg;
    const unsigned short* p1 = h16 + (size_t)e1.x * HID + cg;
    uint4 a0 = *(const uint4*)p0, b0 = *(const uint4*)(p0 + 8);
    uint4 a1 = *(const uint4*)p1, b1 = *(const uint4*)(p1 + 8);
    float w0 = __int_as_float(e0.y), w1 = __int_as_float(e1.y);
    ACC16(a0, b0, w0);
    ACC16(a1, b1, w1);
  }
  if (i < e) {
    int2 e0 = edata[i];
    const unsigned short* p0 = h16 + (size_t)e0.x * HID + cg;
    uint4 a0 = *(const uint4*)p0, b0 = *(const uint4*)(p0 + 8);
    ACC16(a0, b0, __int_as_float(e0.y));
  }
#undef ACC16

#pragma unroll
  for (int q = 0; q < 16; ++q) {
    acc[q] += __shfl_xor(acc[q], 8);
    acc[q] += __shfl_xor(acc[q], 16);
    acc[q] += __shfl_xor(acc[q], 32);
  }

  if (lane < 8) {
    size_t nc = (size_t)n * HID + cg;
    const uint4 xa = *(const uint4*)(x016 + nc);
    const uint4 xb = *(const uint4*)(x016 + nc + 8);
    float o[16];
    o[0]  = 0.5f * acc[0]  + 0.5f * bflo(xa.x);
    o[1]  = 0.5f * acc[1]  + 0.5f * bfhi(xa.x);
    o[2]  = 0.5f * acc[2]  + 0.5f * bflo(xa.y);
    o[3]  = 0.5f * acc[3]  + 0.5f * bfhi(xa.y);
    o[4]  = 0.5f * acc[4]  + 0.5f * bflo(xa.z);
    o[5]  = 0.5f * acc[5]  + 0.5f * bfhi(xa.z);
    o[6]  = 0.5f * acc[6]  + 0.5f * bflo(xa.w);
    o[7]  = 0.5f * acc[7]  + 0.5f * bfhi(xa.w);
    o[8]  = 0.5f * acc[8]  + 0.5f * bflo(xb.x);
    o[9]  = 0.5f * acc[9]  + 0.5f * bfhi(xb.x);
    o[10] = 0.5f * acc[10] + 0.5f * bflo(xb.y);
    o[11] = 0.5f * acc[11] + 0.5f * bfhi(xb.y);
    o[12] = 0.5f * acc[12] + 0.5f * bflo(xb.z);
    o[13] = 0.5f * acc[13] + 0.5f * bfhi(xb.z);
    o[14] = 0.5f * acc[14] + 0.5f * bflo(xb.w);
    o[15] = 0.5f * acc[15] + 0.5f * bfhi(xb.w);
    unsigned short q[16];
#pragma unroll
    for (int t = 0; t < 16; ++t) q[t] = f2bf(o[t]);
    *(uint4*)(hc16 + nc) = *(const uint4*)&q[0];
    *(uint4*)(hc16 + nc + 8) = *(const uint4*)&q[8];
  }
}

// ---------------- host ----------------
extern "C" void kernel_launch(void* const* d_in, const int* in_sizes, int n_in,
                              void* d_out, int out_size, void* d_ws, size_t ws_size,
                              hipStream_t stream) {
  const float* x  = (const float*)d_in[0];
  const int*   ei = (const int*)d_in[1];
  const float* w1 = (const float*)d_in[2];
  const float* b1 = (const float*)d_in[3];
  const float* cw = (const float*)d_in[4];
  const float* w2 = (const float*)d_in[5];
  const float* b2 = (const float*)d_in[6];
  float* out = (float*)d_out;

  char* ws = (char*)d_ws;
  size_t o = 0;
  auto carve = [&](size_t bytes) {
    void* p = ws + o;
    o = (o + bytes + 255) & ~(size_t)255;
    return p;
  };
  int*   cnt    = (int*)carve((size_t)NN * 4);
  float* dinv   = (float*)carve((size_t)NN * 4);
  int*   offs   = (int*)carve((size_t)(NN + 1) * 4);
  int*   cursor = (int*)carve((size_t)NN * 4);
  int*   bsum   = (int*)carve(512 * 4);
  int*   bcnt   = (int*)carve((size_t)NBUCK * 4);
  int*   boffs  = (int*)carve((size_t)(NBUCK + 1) * 4);
  int*   bcur   = (int*)carve((size_t)NBUCK * 4);
  int2*  stage  = (int2*)carve((size_t)NE * 8);
  int2*  edata  = (int2*)carve((size_t)NE * 8);
  unsigned short* x016  = (unsigned short*)carve((size_t)NN * HID * 2);
  unsigned short* hb16  = (unsigned short*)carve((size_t)NN * HID * 2);
  unsigned short* hcb16 = (unsigned short*)carve((size_t)NN * HID * 2);
  unsigned short* wt1   = (unsigned short*)carve((size_t)INCH * HID * 2);
  unsigned short* wtl   = (unsigned short*)carve((size_t)NLAYERS * HID * HID * 2);
  unsigned short* wt2   = (unsigned short*)carve((size_t)48 * HID * 2);
  (void)ws_size; (void)in_sizes; (void)n_in; (void)out_size;

  const int TB = 256;
  const int gN = (NN + TB - 1) / TB;     // 391
  const int gEB = (NE + EPB - 1) / EPB;  // 391

  k_zero<<<gN, TB, 0, stream>>>(cnt, bcnt);
  k_bcnt<<<gEB, TB, 0, stream>>>(ei, cnt, bcnt);
  k_dinv<<<gN, TB, 0, stream>>>(cnt, dinv, offs);
  k_scan1<<<gN, TB, 0, stream>>>(cnt, bsum);
  k_scan2<<<1, 512, 0, stream>>>(bsum, gN);
  k_scan3<<<gN, TB, 0, stream>>>(cnt, bsum, offs, cursor);
  k_bscan<<<1, 512, 0, stream>>>(bcnt, boffs, bcur);
  k_passA<<<gEB, TB, 0, stream>>>(ei, bcur, stage);
  k_passB<<<NBUCK, TB, 0, stream>>>(stage, boffs, offs, dinv, cursor, edata);

  k_cvtw<<<(INCH * HID + 255) / 256, 256, 0, stream>>>(w1, wt1, INCH);
  k_cvtw8<<<(NLAYERS * HID * HID + 255) / 256, 256, 0, stream>>>(cw, wtl);
  k_cvtw2<<<(48 * HID + 255) / 256, 256, 0, stream>>>(w2, wt2);

  k_lin1<<<(NN + 31) / 32, 256, 0, stream>>>(x, wt1, b1, x016, NN);

  const unsigned short* hin = x016;
  const int gA = (NN + 3) / 4;  // 25000
  for (int l = 0; l < NLAYERS; ++l) {
    float beta = logf(1.0f / (float)(l + 1) + 1.0f);
    k_agg<<<gA, 256, 0, stream>>>(hin, x016, dinv, offs, edata, hcb16);
    k_mgemm1<<<(NN + 31) / 32, 256, 0, stream>>>(
        hcb16, wtl + (size_t)l * HID * HID, beta, hb16, NN);
    hin = hb16;
  }
  k_mlin2<<<(NN + 63) / 64, 256, 0, stream>>>(hb16, wt2, b2, out);
}

// Round 8
// 861.763 us; speedup vs baseline: 3.4261x; 1.2060x over previous
//
#include <hip/hip_runtime.h>
#include <math.h>

#define NN 100000
#define NE 1600000
#define HID 128
#define INCH 256
#define OUTC 40
#define NLAYERS 8
#define NBUCK 391   // ceil(NN/256)
#define EPB 4096
#define CAP 6144
#define LW 136      // LDS row stride in ushorts (272 B, 16B-aligned, bank-spread)

typedef __attribute__((ext_vector_type(8))) short bf16x8;
typedef __attribute__((ext_vector_type(4))) float f32x4;

static __device__ inline unsigned short f2bf(float f) {
  unsigned u = __float_as_uint(f);
  unsigned r = (u + 0x7fff + ((u >> 16) & 1)) >> 16;
  return (unsigned short)r;
}
static __device__ inline float bflo(unsigned u) { return __uint_as_float(u << 16); }
static __device__ inline float bfhi(unsigned u) { return __uint_as_float(u & 0xffff0000u); }

// ---------------- preprocessing ----------------

static __global__ void k_zero(int* __restrict__ cnt, int* __restrict__ bcnt) {
  int i = blockIdx.x * 256 + threadIdx.x;
  if (i < NN) cnt[i] = 0;
  if (i < NBUCK) bcnt[i] = 0;
}

static __global__ __launch_bounds__(256) void k_bcnt(const int* __restrict__ ei,
                                                     int* __restrict__ cnt,
                                                     int* __restrict__ bcnt) {
  __shared__ int lh[512];
  int t = threadIdx.x;
  for (int i = t; i < 512; i += 256) lh[i] = 0;
  __syncthreads();
  int e0 = blockIdx.x * EPB;
  for (int k = t; k < EPB; k += 256) {
    int e = e0 + k;
    if (e < NE) {
      int d = ei[NE + e];
      atomicAdd(&cnt[d], 1);
      atomicAdd(&lh[d >> 8], 1);
    }
  }
  __syncthreads();
  for (int i = t; i < NBUCK; i += 256)
    if (lh[i]) atomicAdd(&bcnt[i], lh[i]);
}

static __global__ void k_dinv(const int* __restrict__ cnt, float* __restrict__ dinv,
                              int* __restrict__ offs) {
  int i = blockIdx.x * 256 + threadIdx.x;
  if (i < NN) dinv[i] = rsqrtf((float)(cnt[i] + 1));
  if (blockIdx.x == 0 && threadIdx.x == 0) offs[NN] = NE;
}

static __global__ void k_scan1(const int* __restrict__ cnt, int* __restrict__ bsum) {
  __shared__ int sd[256];
  int t = threadIdx.x;
  int gid = blockIdx.x * 256 + t;
  sd[t] = (gid < NN) ? cnt[gid] : 0;
  __syncthreads();
  for (int s = 128; s > 0; s >>= 1) {
    if (t < s) sd[t] += sd[t + s];
    __syncthreads();
  }
  if (t == 0) bsum[blockIdx.x] = sd[0];
}

static __global__ void k_scan2(int* __restrict__ bsum, int nb) {
  __shared__ int sd[512];
  int t = threadIdx.x;
  sd[t] = (t < nb) ? bsum[t] : 0;
  __syncthreads();
  for (int d = 1; d < 512; d <<= 1) {
    int v = (t >= d) ? sd[t - d] : 0;
    __syncthreads();
    sd[t] += v;
    __syncthreads();
  }
  if (t < nb) bsum[t] = sd[t];
}

static __global__ void k_scan3(const int* __restrict__ cnt, const int* __restrict__ bsum,
                               int* __restrict__ offs, int* __restrict__ cursor) {
  __shared__ int sd[256];
  int t = threadIdx.x;
  int gid = blockIdx.x * 256 + t;
  int v = (gid < NN) ? cnt[gid] : 0;
  sd[t] = v;
  __syncthreads();
  for (int d = 1; d < 256; d <<= 1) {
    int u = (t >= d) ? sd[t - d] : 0;
    __syncthreads();
    sd[t] += u;
    __syncthreads();
  }
  int base = (blockIdx.x > 0) ? bsum[blockIdx.x - 1] : 0;
  int excl = base + sd[t] - v;
  if (gid < NN) { offs[gid] = excl; cursor[gid] = excl; }
}

static __global__ void k_bscan(const int* __restrict__ bcnt, int* __restrict__ boffs,
                               int* __restrict__ bcur) {
  __shared__ int sd[512];
  int t = threadIdx.x;
  sd[t] = (t < NBUCK) ? bcnt[t] : 0;
  __syncthreads();
  for (int d = 1; d < 512; d <<= 1) {
    int v = (t >= d) ? sd[t - d] : 0;
    __syncthreads();
    sd[t] += v;
    __syncthreads();
  }
  if (t < NBUCK) {
    boffs[t + 1] = sd[t];
    bcur[t] = sd[t] - bcnt[t];
  }
  if (t == 0) boffs[0] = 0;
}

static __global__ __launch_bounds__(256) void k_passA(const int* __restrict__ ei,
                                                      int* __restrict__ bcur,
                                                      int2* __restrict__ stage) {
  __shared__ int lh[512], lbase[512], lcur[512];
  int t = threadIdx.x;
  int e0 = blockIdx.x * EPB;
  for (int i = t; i < 512; i += 256) lh[i] = 0;
  __syncthreads();
  for (int k = t; k < EPB; k += 256) {
    int e = e0 + k;
    if (e < NE) atomicAdd(&lh[ei[NE + e] >> 8], 1);
  }
  __syncthreads();
  for (int i = t; i < NBUCK; i += 256) {
    int c = lh[i];
    lbase[i] = c ? atomicAdd(&bcur[i], c) : 0;
    lcur[i] = 0;
  }
  __syncthreads();
  for (int k = t; k < EPB; k += 256) {
    int e = e0 + k;
    if (e < NE) {
      int s = ei[e], d = ei[NE + e];
      int bu = d >> 8;
      int r = atomicAdd(&lcur[bu], 1);
      stage[lbase[bu] + r] = make_int2(s, d);
    }
  }
}

static __global__ __launch_bounds__(256) void k_passB(
    const int2* __restrict__ stage, const int* __restrict__ boffs,
    const int* __restrict__ offs, const float* __restrict__ dinv,
    int* __restrict__ cursor, int2* __restrict__ edata) {
  __shared__ int2 lbuf[CAP];
  __shared__ int lcur[256];
  int b = blockIdx.x, t = threadIdx.x;
  int sb = boffs[b], se = boffs[b + 1];
  int cntb = se - sb;
  int nb0 = b << 8;
  int off0 = offs[nb0];
  if (cntb <= CAP) {
    if (t < 256 && nb0 + t < NN) lcur[t] = offs[nb0 + t] - off0;
    __syncthreads();
    for (int k = t; k < cntb; k += 256) {
      int2 sd_ = stage[sb + k];
      float w = dinv[sd_.x] * dinv[sd_.y];
      int p = atomicAdd(&lcur[sd_.y - nb0], 1);
      lbuf[p] = make_int2(sd_.x, __float_as_int(w));
    }
    __syncthreads();
    for (int k = t; k < cntb; k += 256) edata[off0 + k] = lbuf[k];
  } else {
    for (int k = t; k < cntb; k += 256) {
      int2 sd_ = stage[sb + k];
      float w = dinv[sd_.x] * dinv[sd_.y];
      int p = atomicAdd(&cursor[sd_.y], 1);
      edata[p] = make_int2(sd_.x, __float_as_int(w));
    }
  }
}

// ---------------- weight conversion ----------------
static __global__ void k_cvtw(const float* __restrict__ W, unsigned short* __restrict__ Wt,
                              int K) {
  int idx = blockIdx.x * 256 + threadIdx.x;
  if (idx < K * HID) {
    int k = idx >> 7, n = idx & 127;
    Wt[(size_t)n * K + k] = f2bf(W[idx]);
  }
}

// Folded layer weights: W'_l = beta_l * W_l + (1-beta_l) * I, transposed [n][k]
static __global__ void k_cvtw8(const float* __restrict__ W, unsigned short* __restrict__ Wt) {
  int idx = blockIdx.x * 256 + threadIdx.x;
  if (idx < NLAYERS * HID * HID) {
    int l = idx >> 14, rem = idx & 16383;
    int k = rem >> 7, n = rem & 127;
    float beta = logf(1.0f / (float)(l + 1) + 1.0f);
    float v = beta * W[idx];
    if (k == n) v += 1.0f - beta;
    Wt[(size_t)l * HID * HID + n * HID + k] = f2bf(v);
  }
}

static __global__ void k_cvtw2(const float* __restrict__ W2, unsigned short* __restrict__ Wt2) {
  int idx = blockIdx.x * 256 + threadIdx.x;
  if (idx < 48 * HID) {
    int n = idx >> 7, k = idx & 127;
    Wt2[idx] = (n < OUTC) ? f2bf(W2[(size_t)k * OUTC + n]) : 0;
  }
}

// ---------------- lin1: C16[M x 128] = bf16(relu(A32[M x 256] @ W + bias)) ----------------
// 128-row tile staged in LDS (f32->bf16 on stage), 2 K-chunks of 128.
// 4 waves: wave = 64 rows x 64 cols, 4 row-tiles of 16.
__global__ __launch_bounds__(256, 3) void k_lin1(
    const float* __restrict__ A32, const unsigned short* __restrict__ Wt16,
    const float* __restrict__ bias, unsigned short* __restrict__ C16, int M) {
  __shared__ unsigned short lds[128 * LW];
  const int tid = threadIdx.x;
  const int lane = tid & 63;
  const int wid = tid >> 6;
  const int j = lane & 15, g = lane >> 4;
  const int rowhalf = (wid >> 1) * 64;
  const int colbase = (wid & 1) * 64;
  const int m0 = blockIdx.x * 128;

  f32x4 acc[4][4];
  const f32x4 zero = {0.f, 0.f, 0.f, 0.f};
#pragma unroll
  for (int rt = 0; rt < 4; ++rt)
#pragma unroll
    for (int c = 0; c < 4; ++c) acc[rt][c] = zero;

#pragma unroll 1
  for (int kc = 0; kc < 2; ++kc) {
    bf16x8 bfrag[4][4];
#pragma unroll
    for (int c = 0; c < 4; ++c)
#pragma unroll
      for (int s = 0; s < 4; ++s)
        bfrag[c][s] = *(const bf16x8*)(Wt16 + (size_t)(colbase + 16 * c + j) * INCH +
                                       kc * 128 + 32 * s + 8 * g);
    __syncthreads();  // prior-kc LDS reads done before restage
#pragma unroll 2
    for (int i = 0; i < 8; ++i) {
      int idx = i * 256 + tid;      // 0..2047
      int row = idx >> 4, ch = idx & 15;
      int grow = m0 + row;
      if (grow >= M) grow = M - 1;
      const float* p = A32 + (size_t)grow * INCH + kc * 128 + ch * 8;
      float4 u0 = *(const float4*)p;
      float4 u1 = *(const float4*)(p + 4);
      bf16x8 v;
      v[0] = (short)f2bf(u0.x); v[1] = (short)f2bf(u0.y);
      v[2] = (short)f2bf(u0.z); v[3] = (short)f2bf(u0.w);
      v[4] = (short)f2bf(u1.x); v[5] = (short)f2bf(u1.y);
      v[6] = (short)f2bf(u1.z); v[7] = (short)f2bf(u1.w);
      *(bf16x8*)&lds[row * LW + ch * 8] = v;
    }
    __syncthreads();
#pragma unroll
    for (int rt = 0; rt < 4; ++rt) {
      bf16x8 af[4];
#pragma unroll
      for (int s = 0; s < 4; ++s)
        af[s] = *(const bf16x8*)&lds[(rowhalf + rt * 16 + j) * LW + 32 * s + 8 * g];
#pragma unroll
      for (int s = 0; s < 4; ++s)
#pragma unroll
        for (int c = 0; c < 4; ++c)
          acc[rt][c] =
              __builtin_amdgcn_mfma_f32_16x16x32_bf16(af[s], bfrag[c][s], acc[rt][c], 0, 0, 0);
    }
  }

#pragma unroll
  for (int rt = 0; rt < 4; ++rt)
#pragma unroll
    for (int i = 0; i < 4; ++i) {
      const int rr = m0 + rowhalf + rt * 16 + 4 * g + i;
      if (rr >= M) continue;
#pragma unroll
      for (int c = 0; c < 4; ++c) {
        const int col = colbase + 16 * c + j;
        float z = fmaxf(acc[rt][c][i] + bias[col], 0.f);
        C16[(size_t)rr * HID + col] = f2bf(z);
      }
    }
}

// ---------------- layer GEMM: C16 = bf16(relu(A16 @ W')) (skip folded into W') ----------------
__global__ __launch_bounds__(256, 3) void k_mgemm1(
    const unsigned short* __restrict__ A16, const unsigned short* __restrict__ Wt16,
    unsigned short* __restrict__ C16, int M) {
  __shared__ unsigned short lds[128 * LW];
  const int tid = threadIdx.x;
  const int lane = tid & 63;
  const int wid = tid >> 6;
  const int j = lane & 15, g = lane >> 4;
  const int rowhalf = (wid >> 1) * 64;
  const int colbase = (wid & 1) * 64;
  const int m0 = blockIdx.x * 128;

  bf16x8 bfrag[4][4];
#pragma unroll
  for (int c = 0; c < 4; ++c)
#pragma unroll
    for (int s = 0; s < 4; ++s)
      bfrag[c][s] =
          *(const bf16x8*)(Wt16 + (size_t)(colbase + 16 * c + j) * HID + 32 * s + 8 * g);

#pragma unroll 2
  for (int i = 0; i < 8; ++i) {
    int idx = i * 256 + tid;
    int row = idx >> 4, ch = idx & 15;
    int grow = m0 + row;
    if (grow >= M) grow = M - 1;
    *(bf16x8*)&lds[row * LW + ch * 8] =
        *(const bf16x8*)(A16 + (size_t)grow * HID + ch * 8);
  }
  __syncthreads();

  f32x4 acc[4][4];
  const f32x4 zero = {0.f, 0.f, 0.f, 0.f};
#pragma unroll
  for (int rt = 0; rt < 4; ++rt) {
    bf16x8 af[4];
#pragma unroll
    for (int s = 0; s < 4; ++s)
      af[s] = *(const bf16x8*)&lds[(rowhalf + rt * 16 + j) * LW + 32 * s + 8 * g];
#pragma unroll
    for (int c = 0; c < 4; ++c) acc[rt][c] = zero;
#pragma unroll
    for (int s = 0; s < 4; ++s)
#pragma unroll
      for (int c = 0; c < 4; ++c)
        acc[rt][c] =
            __builtin_amdgcn_mfma_f32_16x16x32_bf16(af[s], bfrag[c][s], acc[rt][c], 0, 0, 0);
  }

#pragma unroll
  for (int rt = 0; rt < 4; ++rt)
#pragma unroll
    for (int i = 0; i < 4; ++i) {
      const int rr = m0 + rowhalf + rt * 16 + 4 * g + i;
      if (rr >= M) continue;
#pragma unroll
      for (int c = 0; c < 4; ++c) {
        const int col = colbase + 16 * c + j;
        float z = fmaxf(acc[rt][c][i], 0.f);
        C16[(size_t)rr * HID + col] = f2bf(z);
      }
    }
}

// ---------------- fused lin2 + log_softmax via MFMA (LDS-staged A) ----------------
// block = 128 rows; 4 waves x 32 rows (2 row-tiles); 48 padded cols (CT=3).
static __global__ __launch_bounds__(256, 3) void k_mlin2(
    const unsigned short* __restrict__ h16, const unsigned short* __restrict__ Wt2,
    const float* __restrict__ b2, float* __restrict__ out) {
  __shared__ unsigned short lds[128 * LW];
  const int tid = threadIdx.x;
  const int lane = tid & 63;
  const int wid = tid >> 6;
  const int j = lane & 15, g = lane >> 4;
  const int m0 = blockIdx.x * 128;

  bf16x8 bfrag[3][4];
#pragma unroll
  for (int c = 0; c < 3; ++c)
#pragma unroll
    for (int s = 0; s < 4; ++s)
      bfrag[c][s] = *(const bf16x8*)(Wt2 + (size_t)(16 * c + j) * HID + 32 * s + 8 * g);

  float bb[3];
#pragma unroll
  for (int c = 0; c < 3; ++c) {
    int col = 16 * c + j;
    bb[c] = (col < OUTC) ? b2[col] : -1e30f;
  }

#pragma unroll 2
  for (int i = 0; i < 8; ++i) {
    int idx = i * 256 + tid;
    int row = idx >> 4, ch = idx & 15;
    int grow = m0 + row;
    if (grow >= NN) grow = NN - 1;
    *(bf16x8*)&lds[row * LW + ch * 8] =
        *(const bf16x8*)(h16 + (size_t)grow * HID + ch * 8);
  }
  __syncthreads();

  const f32x4 zero = {0.f, 0.f, 0.f, 0.f};
#pragma unroll
  for (int rt = 0; rt < 2; ++rt) {
    bf16x8 af[4];
#pragma unroll
    for (int s = 0; s < 4; ++s)
      af[s] = *(const bf16x8*)&lds[(wid * 32 + rt * 16 + j) * LW + 32 * s + 8 * g];
    f32x4 acc[3] = {zero, zero, zero};
#pragma unroll
    for (int s = 0; s < 4; ++s)
#pragma unroll
      for (int c = 0; c < 3; ++c)
        acc[c] = __builtin_amdgcn_mfma_f32_16x16x32_bf16(af[s], bfrag[c][s], acc[c], 0, 0, 0);

#pragma unroll
    for (int i = 0; i < 4; ++i) {
      const int rr = m0 + wid * 32 + rt * 16 + 4 * g + i;
      float z0 = acc[0][i] + bb[0];
      float z1 = acc[1][i] + bb[1];
      float z2 = acc[2][i] + bb[2];
      float m = fmaxf(fmaxf(z0, z1), z2);
      m = fmaxf(m, __shfl_xor(m, 1));
      m = fmaxf(m, __shfl_xor(m, 2));
      m = fmaxf(m, __shfl_xor(m, 4));
      m = fmaxf(m, __shfl_xor(m, 8));
      float sum = __expf(z0 - m) + __expf(z1 - m) + __expf(z2 - m);
      sum += __shfl_xor(sum, 1);
      sum += __shfl_xor(sum, 2);
      sum += __shfl_xor(sum, 4);
      sum += __shfl_xor(sum, 8);
      float ls = m + logf(sum);
      if (rr < NN) {
        out[(size_t)rr * OUTC + j] = z0 - ls;
        out[(size_t)rr * OUTC + 16 + j] = z1 - ls;
        if (j < 8) out[(size_t)rr * OUTC + 32 + j] = z2 - ls;
      }
    }
  }
}

// ---------------- aggregation: hc16 = bf16(0.5*(A_hat @ h16) + 0.5*x016) ----------------
static __global__ __launch_bounds__(256) void k_agg(
    const unsigned short* __restrict__ h16, const unsigned short* __restrict__ x016,
    const float* __restrict__ dinv, const int* __restrict__ offs,
    const int2* __restrict__ edata, unsigned short* __restrict__ hc16) {
  int wid = threadIdx.x >> 6;
  int n = blockIdx.x * 4 + wid;
  if (n >= NN) return;
  int lane = threadIdx.x & 63;
  int cg = (lane & 7) * 16;
  int slot = lane >> 3;

  int b = offs[n], e = offs[n + 1];
  float acc[16];
#pragma unroll
  for (int q = 0; q < 16; ++q) acc[q] = 0.f;

#define ACC16(VA, VB, W)                                               \
  {                                                                    \
    acc[0]  = fmaf((W), bflo((VA).x), acc[0]);                         \
    acc[1]  = fmaf((W), bfhi((VA).x), acc[1]);                         \
    acc[2]  = fmaf((W), bflo((VA).y), acc[2]);                         \
    acc[3]  = fmaf((W), bfhi((VA).y), acc[3]);                         \
    acc[4]  = fmaf((W), bflo((VA).z), acc[4]);                         \
    acc[5]  = fmaf((W), bfhi((VA).z), acc[5]);                         \
    acc[6]  = fmaf((W), bflo((VA).w), acc[6]);                         \
    acc[7]  = fmaf((W), bfhi((VA).w), acc[7]);                         \
    acc[8]  = fmaf((W), bflo((VB).x), acc[8]);                         \
    acc[9]  = fmaf((W), bfhi((VB).x), acc[9]);                         \
    acc[10] = fmaf((W), bflo((VB).y), acc[10]);                        \
    acc[11] = fmaf((W), bfhi((VB).y), acc[11]);                        \
    acc[12] = fmaf((W), bflo((VB).z), acc[12]);                        \
    acc[13] = fmaf((W), bfhi((VB).z), acc[13]);                        \
    acc[14] = fmaf((W), bflo((VB).w), acc[14]);                        \
    acc[15] = fmaf((W), bfhi((VB).w), acc[15]);                        \
  }

  if (slot == 0) {
    float dn = dinv[n];
    const unsigned short* p = h16 + (size_t)n * HID + cg;
    uint4 va = *(const uint4*)p, vb = *(const uint4*)(p + 8);
    ACC16(va, vb, dn * dn);
  }
  int i = b + slot;
  for (; i + 8 < e; i += 16) {
    int2 e0 = edata[i], e1 = edata[i + 8];
    const unsigned short* p0 = h16 + (size_t)e0.x * HID + cg;
    const unsigned short* p1 = h16 + (size_t)e1.x * HID + cg;
    uint4 a0 = *(const uint4*)p0, b0 = *(const uint4*)(p0 + 8);
    uint4 a1 = *(const uint4*)p1, b1 = *(const uint4*)(p1 + 8);
    float w0 = __int_as_float(e0.y), w1 = __int_as_float(e1.y);
    ACC16(a0, b0, w0);
    ACC16(a1, b1, w1);
  }
  if (i < e) {
    int2 e0 = edata[i];
    const unsigned short* p0 = h16 + (size_t)e0.x * HID + cg;
    uint4 a0 = *(const uint4*)p0, b0 = *(const uint4*)(p0 + 8);
    ACC16(a0, b0, __int_as_float(e0.y));
  }
#undef ACC16

#pragma unroll
  for (int q = 0; q < 16; ++q) {
    acc[q] += __shfl_xor(acc[q], 8);
    acc[q] += __shfl_xor(acc[q], 16);
    acc[q] += __shfl_xor(acc[q], 32);
  }

  if (lane < 8) {
    size_t nc = (size_t)n * HID + cg;
    const uint4 xa = *(const uint4*)(x016 + nc);
    const uint4 xb = *(const uint4*)(x016 + nc + 8);
    float o[16];
    o[0]  = 0.5f * acc[0]  + 0.5f * bflo(xa.x);
    o[1]  = 0.5f * acc[1]  + 0.5f * bfhi(xa.x);
    o[2]  = 0.5f * acc[2]  + 0.5f * bflo(xa.y);
    o[3]  = 0.5f * acc[3]  + 0.5f * bfhi(xa.y);
    o[4]  = 0.5f * acc[4]  + 0.5f * bflo(xa.z);
    o[5]  = 0.5f * acc[5]  + 0.5f * bfhi(xa.z);
    o[6]  = 0.5f * acc[6]  + 0.5f * bflo(xa.w);
    o[7]  = 0.5f * acc[7]  + 0.5f * bfhi(xa.w);
    o[8]  = 0.5f * acc[8]  + 0.5f * bflo(xb.x);
    o[9]  = 0.5f * acc[9]  + 0.5f * bfhi(xb.x);
    o[10] = 0.5f * acc[10] + 0.5f * bflo(xb.y);
    o[11] = 0.5f * acc[11] + 0.5f * bfhi(xb.y);
    o[12] = 0.5f * acc[12] + 0.5f * bflo(xb.z);
    o[13] = 0.5f * acc[13] + 0.5f * bfhi(xb.z);
    o[14] = 0.5f * acc[14] + 0.5f * bflo(xb.w);
    o[15] = 0.5f * acc[15] + 0.5f * bfhi(xb.w);
    unsigned short q[16];
#pragma unroll
    for (int t = 0; t < 16; ++t) q[t] = f2bf(o[t]);
    *(uint4*)(hc16 + nc) = *(const uint4*)&q[0];
    *(uint4*)(hc16 + nc + 8) = *(const uint4*)&q[8];
  }
}

// ---------------- host ----------------
extern "C" void kernel_launch(void* const* d_in, const int* in_sizes, int n_in,
                              void* d_out, int out_size, void* d_ws, size_t ws_size,
                              hipStream_t stream) {
  const float* x  = (const float*)d_in[0];
  const int*   ei = (const int*)d_in[1];
  const float* w1 = (const float*)d_in[2];
  const float* b1 = (const float*)d_in[3];
  const float* cw = (const float*)d_in[4];
  const float* w2 = (const float*)d_in[5];
  const float* b2 = (const float*)d_in[6];
  float* out = (float*)d_out;

  char* ws = (char*)d_ws;
  size_t o = 0;
  auto carve = [&](size_t bytes) {
    void* p = ws + o;
    o = (o + bytes + 255) & ~(size_t)255;
    return p;
  };
  int*   cnt    = (int*)carve((size_t)NN * 4);
  float* dinv   = (float*)carve((size_t)NN * 4);
  int*   offs   = (int*)carve((size_t)(NN + 1) * 4);
  int*   cursor = (int*)carve((size_t)NN * 4);
  int*   bsum   = (int*)carve(512 * 4);
  int*   bcnt   = (int*)carve((size_t)NBUCK * 4);
  int*   boffs  = (int*)carve((size_t)(NBUCK + 1) * 4);
  int*   bcur   = (int*)carve((size_t)NBUCK * 4);
  int2*  stage  = (int2*)carve((size_t)NE * 8);
  int2*  edata  = (int2*)carve((size_t)NE * 8);
  unsigned short* x016  = (unsigned short*)carve((size_t)NN * HID * 2);
  unsigned short* hb16  = (unsigned short*)carve((size_t)NN * HID * 2);
  unsigned short* hcb16 = (unsigned short*)carve((size_t)NN * HID * 2);
  unsigned short* wt1   = (unsigned short*)carve((size_t)INCH * HID * 2);
  unsigned short* wtl   = (unsigned short*)carve((size_t)NLAYERS * HID * HID * 2);
  unsigned short* wt2   = (unsigned short*)carve((size_t)48 * HID * 2);
  (void)ws_size; (void)in_sizes; (void)n_in; (void)out_size;

  const int TB = 256;
  const int gN = (NN + TB - 1) / TB;     // 391
  const int gEB = (NE + EPB - 1) / EPB;  // 391

  k_zero<<<gN, TB, 0, stream>>>(cnt, bcnt);
  k_bcnt<<<gEB, TB, 0, stream>>>(ei, cnt, bcnt);
  k_dinv<<<gN, TB, 0, stream>>>(cnt, dinv, offs);
  k_scan1<<<gN, TB, 0, stream>>>(cnt, bsum);
  k_scan2<<<1, 512, 0, stream>>>(bsum, gN);
  k_scan3<<<gN, TB, 0, stream>>>(cnt, bsum, offs, cursor);
  k_bscan<<<1, 512, 0, stream>>>(bcnt, boffs, bcur);
  k_passA<<<gEB, TB, 0, stream>>>(ei, bcur, stage);
  k_passB<<<NBUCK, TB, 0, stream>>>(stage, boffs, offs, dinv, cursor, edata);

  k_cvtw<<<(INCH * HID + 255) / 256, 256, 0, stream>>>(w1, wt1, INCH);
  k_cvtw8<<<(NLAYERS * HID * HID + 255) / 256, 256, 0, stream>>>(cw, wtl);
  k_cvtw2<<<(48 * HID + 255) / 256, 256, 0, stream>>>(w2, wt2);

  const int gG = (NN + 127) / 128;  // 782
  k_lin1<<<gG, 256, 0, stream>>>(x, wt1, b1, x016, NN);

  const unsigned short* hin = x016;
  const int gA = (NN + 3) / 4;  // 25000
  for (int l = 0; l < NLAYERS; ++l) {
    k_agg<<<gA, 256, 0, stream>>>(hin, x016, dinv, offs, edata, hcb16);
    k_mgemm1<<<gG, 256, 0, stream>>>(hcb16, wtl + (size_t)l * HID * HID, hb16, NN);
    hin = hb16;
  }
  k_mlin2<<<gG, 256, 0, stream>>>(hb16, wt2, b2, out);
}

// Round 9
// 802.041 us; speedup vs baseline: 3.6812x; 1.0745x over previous
//
#include <hip/hip_runtime.h>
#include <math.h>

#define NN 100000
#define NE 1600000
#define HID 128
#define INCH 256
#define OUTC 40
#define NLAYERS 8
#define NBUCK 391   // ceil(NN/256)
#define EPB 4096
#define CAP 6144
#define LW 136      // LDS row stride in ushorts (272 B)

typedef __attribute__((ext_vector_type(8))) short bf16x8;
typedef __attribute__((ext_vector_type(4))) float f32x4;

static __device__ inline unsigned short f2bf(float f) {
  unsigned u = __float_as_uint(f);
  unsigned r = (u + 0x7fff + ((u >> 16) & 1)) >> 16;
  return (unsigned short)r;
}
static __device__ inline float bflo(unsigned u) { return __uint_as_float(u << 16); }
static __device__ inline float bfhi(unsigned u) { return __uint_as_float(u & 0xffff0000u); }

// ---------------- preprocessing (atomic-light counting sort) ----------------

static __global__ void k_zerob(int* __restrict__ bcnt) {
  int i = blockIdx.x * 256 + threadIdx.x;
  if (i < NBUCK) bcnt[i] = 0;
}

// bucket histogram: LDS atomics only + NBUCK global adds per block
static __global__ __launch_bounds__(256) void k_bhist(const int* __restrict__ ei,
                                                      int* __restrict__ bcnt) {
  __shared__ int lh[NBUCK + 1];
  int t = threadIdx.x;
  for (int i = t; i <= NBUCK; i += 256) lh[i] = 0;
  __syncthreads();
  int e0 = blockIdx.x * EPB;
  for (int k = t; k < EPB; k += 256) {
    int e = e0 + k;
    if (e < NE) atomicAdd(&lh[ei[NE + e] >> 8], 1);
  }
  __syncthreads();
  for (int i = t; i < NBUCK; i += 256)
    if (lh[i]) atomicAdd(&bcnt[i], lh[i]);
}

static __global__ void k_bscan(const int* __restrict__ bcnt, int* __restrict__ boffs,
                               int* __restrict__ bcur, int* __restrict__ offs) {
  __shared__ int sd[512];
  int t = threadIdx.x;
  sd[t] = (t < NBUCK) ? bcnt[t] : 0;
  __syncthreads();
  for (int d = 1; d < 512; d <<= 1) {
    int v = (t >= d) ? sd[t - d] : 0;
    __syncthreads();
    sd[t] += v;
    __syncthreads();
  }
  if (t < NBUCK) {
    boffs[t + 1] = sd[t];
    bcur[t] = sd[t] - bcnt[t];
  }
  if (t == 0) { boffs[0] = 0; offs[NN] = NE; }
}

// stage edges in LDS (single ei read), LDS hist, bucket-contiguous scatter
static __global__ __launch_bounds__(256) void k_sortA(const int* __restrict__ ei,
                                                      int* __restrict__ bcur,
                                                      int2* __restrict__ stage) {
  __shared__ int lsrc[EPB], ldst[EPB];
  __shared__ int lh[NBUCK + 1], lbase[NBUCK + 1], lcur[NBUCK + 1];
  int t = threadIdx.x;
  int e0 = blockIdx.x * EPB;
  for (int k = t; k < EPB; k += 256) {
    int e = e0 + k;
    lsrc[k] = (e < NE) ? ei[e] : -1;
    ldst[k] = (e < NE) ? ei[NE + e] : -1;
  }
  for (int i = t; i <= NBUCK; i += 256) lh[i] = 0;
  __syncthreads();
  for (int k = t; k < EPB; k += 256)
    if (ldst[k] >= 0) atomicAdd(&lh[ldst[k] >> 8], 1);
  __syncthreads();
  for (int i = t; i < NBUCK; i += 256) {
    int c = lh[i];
    lbase[i] = c ? atomicAdd(&bcur[i], c) : 0;
    lcur[i] = 0;
  }
  __syncthreads();
  for (int k = t; k < EPB; k += 256) {
    int d = ldst[k];
    if (d >= 0) {
      int bu = d >> 8;
      int r = atomicAdd(&lcur[bu], 1);
      stage[lbase[bu] + r] = make_int2(lsrc[k], d);
    }
  }
}

// per-bucket degrees -> offs, dinv, cursor (no global hist needed)
static __global__ __launch_bounds__(256) void k_degs(
    const int2* __restrict__ stage, const int* __restrict__ boffs,
    int* __restrict__ offs, float* __restrict__ dinv, int* __restrict__ cursor) {
  __shared__ int lcnt[256];
  __shared__ int sd[256];
  int b = blockIdx.x, t = threadIdx.x;
  int sb = boffs[b], se = boffs[b + 1];
  int cntb = se - sb;
  int nb0 = b << 8;
  lcnt[t] = 0;
  __syncthreads();
  for (int k = t; k < cntb; k += 256) atomicAdd(&lcnt[stage[sb + k].y - nb0], 1);
  __syncthreads();
  int v = lcnt[t];
  sd[t] = v;
  __syncthreads();
  for (int d = 1; d < 256; d <<= 1) {
    int u = (t >= d) ? sd[t - d] : 0;
    __syncthreads();
    sd[t] += u;
    __syncthreads();
  }
  int n = nb0 + t;
  if (n < NN) {
    int o = sb + sd[t] - v;
    offs[n] = o;
    cursor[n] = o;
    dinv[n] = rsqrtf((float)(v + 1));
  }
}

// within-bucket LDS scatter -> sequential edata writes (+ weights)
static __global__ __launch_bounds__(256) void k_passB2(
    const int2* __restrict__ stage, const int* __restrict__ boffs,
    const int* __restrict__ offs, const float* __restrict__ dinv,
    int* __restrict__ cursor, int2* __restrict__ edata) {
  __shared__ int2 lbuf[CAP];
  __shared__ int lcur[256];
  int b = blockIdx.x, t = threadIdx.x;
  int sb = boffs[b], se = boffs[b + 1];
  int cntb = se - sb;
  int nb0 = b << 8;
  if (cntb <= CAP) {
    if (nb0 + t < NN) lcur[t] = offs[nb0 + t] - sb;
    __syncthreads();
    for (int k = t; k < cntb; k += 256) {
      int2 sd_ = stage[sb + k];
      float w = dinv[sd_.x] * dinv[sd_.y];
      int p = atomicAdd(&lcur[sd_.y - nb0], 1);
      lbuf[p] = make_int2(sd_.x, __float_as_int(w));
    }
    __syncthreads();
    for (int k = t; k < cntb; k += 256) edata[sb + k] = lbuf[k];
  } else {  // fallback, never expected
    for (int k = t; k < cntb; k += 256) {
      int2 sd_ = stage[sb + k];
      float w = dinv[sd_.x] * dinv[sd_.y];
      int p = atomicAdd(&cursor[sd_.y], 1);
      edata[p] = make_int2(sd_.x, __float_as_int(w));
    }
  }
}

// ---------------- weight conversion ----------------
static __global__ void k_cvtw(const float* __restrict__ W, unsigned short* __restrict__ Wt,
                              int K) {
  int idx = blockIdx.x * 256 + threadIdx.x;
  if (idx < K * HID) {
    int k = idx >> 7, n = idx & 127;
    Wt[(size_t)n * K + k] = f2bf(W[idx]);
  }
}

// Folded layer weights: W'_l = beta_l * W_l + (1-beta_l) * I, transposed [n][k]
static __global__ void k_cvtw8(const float* __restrict__ W, unsigned short* __restrict__ Wt) {
  int idx = blockIdx.x * 256 + threadIdx.x;
  if (idx < NLAYERS * HID * HID) {
    int l = idx >> 14, rem = idx & 16383;
    int k = rem >> 7, n = rem & 127;
    float beta = logf(1.0f / (float)(l + 1) + 1.0f);
    float v = beta * W[idx];
    if (k == n) v += 1.0f - beta;
    Wt[(size_t)l * HID * HID + n * HID + k] = f2bf(v);
  }
}

static __global__ void k_cvtw2(const float* __restrict__ W2, unsigned short* __restrict__ Wt2) {
  int idx = blockIdx.x * 256 + threadIdx.x;
  if (idx < 48 * HID) {
    int n = idx >> 7, k = idx & 127;
    Wt2[idx] = (n < OUTC) ? f2bf(W2[(size_t)k * OUTC + n]) : 0;
  }
}

// ---------------- lin1: C16[M x 128] = bf16(relu(A32[M x 256] @ W + bias)) ----------------
__global__ __launch_bounds__(256, 3) void k_lin1(
    const float* __restrict__ A32, const unsigned short* __restrict__ Wt16,
    const float* __restrict__ bias, unsigned short* __restrict__ C16, int M) {
  __shared__ unsigned short lds[128 * LW];
  const int tid = threadIdx.x;
  const int lane = tid & 63;
  const int wid = tid >> 6;
  const int j = lane & 15, g = lane >> 4;
  const int rowhalf = (wid >> 1) * 64;
  const int colbase = (wid & 1) * 64;
  const int m0 = blockIdx.x * 128;

  f32x4 acc[4][4];
  const f32x4 zero = {0.f, 0.f, 0.f, 0.f};
#pragma unroll
  for (int rt = 0; rt < 4; ++rt)
#pragma unroll
    for (int c = 0; c < 4; ++c) acc[rt][c] = zero;

#pragma unroll 1
  for (int kc = 0; kc < 2; ++kc) {
    bf16x8 bfrag[4][4];
#pragma unroll
    for (int c = 0; c < 4; ++c)
#pragma unroll
      for (int s = 0; s < 4; ++s)
        bfrag[c][s] = *(const bf16x8*)(Wt16 + (size_t)(colbase + 16 * c + j) * INCH +
                                       kc * 128 + 32 * s + 8 * g);
    __syncthreads();
#pragma unroll 2
    for (int i = 0; i < 8; ++i) {
      int idx = i * 256 + tid;
      int row = idx >> 4, ch = idx & 15;
      int grow = m0 + row;
      if (grow >= M) grow = M - 1;
      const float* p = A32 + (size_t)grow * INCH + kc * 128 + ch * 8;
      float4 u0 = *(const float4*)p;
      float4 u1 = *(const float4*)(p + 4);
      bf16x8 v;
      v[0] = (short)f2bf(u0.x); v[1] = (short)f2bf(u0.y);
      v[2] = (short)f2bf(u0.z); v[3] = (short)f2bf(u0.w);
      v[4] = (short)f2bf(u1.x); v[5] = (short)f2bf(u1.y);
      v[6] = (short)f2bf(u1.z); v[7] = (short)f2bf(u1.w);
      *(bf16x8*)&lds[row * LW + ch * 8] = v;
    }
    __syncthreads();
#pragma unroll
    for (int rt = 0; rt < 4; ++rt) {
      bf16x8 af[4];
#pragma unroll
      for (int s = 0; s < 4; ++s)
        af[s] = *(const bf16x8*)&lds[(rowhalf + rt * 16 + j) * LW + 32 * s + 8 * g];
#pragma unroll
      for (int s = 0; s < 4; ++s)
#pragma unroll
        for (int c = 0; c < 4; ++c)
          acc[rt][c] =
              __builtin_amdgcn_mfma_f32_16x16x32_bf16(af[s], bfrag[c][s], acc[rt][c], 0, 0, 0);
    }
  }

#pragma unroll
  for (int rt = 0; rt < 4; ++rt)
#pragma unroll
    for (int i = 0; i < 4; ++i) {
      const int rr = m0 + rowhalf + rt * 16 + 4 * g + i;
      if (rr >= M) continue;
#pragma unroll
      for (int c = 0; c < 4; ++c) {
        const int col = colbase + 16 * c + j;
        float z = fmaxf(acc[rt][c][i] + bias[col], 0.f);
        C16[(size_t)rr * HID + col] = f2bf(z);
      }
    }
}

// ---------------- layer GEMM: C16 = bf16(relu(A16 @ W')) ----------------
__global__ __launch_bounds__(256, 3) void k_mgemm1(
    const unsigned short* __restrict__ A16, const unsigned short* __restrict__ Wt16,
    unsigned short* __restrict__ C16, int M) {
  __shared__ unsigned short lds[128 * LW];
  const int tid = threadIdx.x;
  const int lane = tid & 63;
  const int wid = tid >> 6;
  const int j = lane & 15, g = lane >> 4;
  const int rowhalf = (wid >> 1) * 64;
  const int colbase = (wid & 1) * 64;
  const int m0 = blockIdx.x * 128;

  bf16x8 bfrag[4][4];
#pragma unroll
  for (int c = 0; c < 4; ++c)
#pragma unroll
    for (int s = 0; s < 4; ++s)
      bfrag[c][s] =
          *(const bf16x8*)(Wt16 + (size_t)(colbase + 16 * c + j) * HID + 32 * s + 8 * g);

#pragma unroll 2
  for (int i = 0; i < 8; ++i) {
    int idx = i * 256 + tid;
    int row = idx >> 4, ch = idx & 15;
    int grow = m0 + row;
    if (grow >= M) grow = M - 1;
    *(bf16x8*)&lds[row * LW + ch * 8] =
        *(const bf16x8*)(A16 + (size_t)grow * HID + ch * 8);
  }
  __syncthreads();

  f32x4 acc[4][4];
  const f32x4 zero = {0.f, 0.f, 0.f, 0.f};
#pragma unroll
  for (int rt = 0; rt < 4; ++rt) {
    bf16x8 af[4];
#pragma unroll
    for (int s = 0; s < 4; ++s)
      af[s] = *(const bf16x8*)&lds[(rowhalf + rt * 16 + j) * LW + 32 * s + 8 * g];
#pragma unroll
    for (int c = 0; c < 4; ++c) acc[rt][c] = zero;
#pragma unroll
    for (int s = 0; s < 4; ++s)
#pragma unroll
      for (int c = 0; c < 4; ++c)
        acc[rt][c] =
            __builtin_amdgcn_mfma_f32_16x16x32_bf16(af[s], bfrag[c][s], acc[rt][c], 0, 0, 0);
  }

#pragma unroll
  for (int rt = 0; rt < 4; ++rt)
#pragma unroll
    for (int i = 0; i < 4; ++i) {
      const int rr = m0 + rowhalf + rt * 16 + 4 * g + i;
      if (rr >= M) continue;
#pragma unroll
      for (int c = 0; c < 4; ++c) {
        const int col = colbase + 16 * c + j;
        float z = fmaxf(acc[rt][c][i], 0.f);
        C16[(size_t)rr * HID + col] = f2bf(z);
      }
    }
}

// ---------------- fused lin2 + log_softmax via MFMA ----------------
static __global__ __launch_bounds__(256, 3) void k_mlin2(
    const unsigned short* __restrict__ h16, const unsigned short* __restrict__ Wt2,
    const float* __restrict__ b2, float* __restrict__ out) {
  __shared__ unsigned short lds[128 * LW];
  const int tid = threadIdx.x;
  const int lane = tid & 63;
  const int wid = tid >> 6;
  const int j = lane & 15, g = lane >> 4;
  const int m0 = blockIdx.x * 128;

  bf16x8 bfrag[3][4];
#pragma unroll
  for (int c = 0; c < 3; ++c)
#pragma unroll
    for (int s = 0; s < 4; ++s)
      bfrag[c][s] = *(const bf16x8*)(Wt2 + (size_t)(16 * c + j) * HID + 32 * s + 8 * g);

  float bb[3];
#pragma unroll
  for (int c = 0; c < 3; ++c) {
    int col = 16 * c + j;
    bb[c] = (col < OUTC) ? b2[col] : -1e30f;
  }

#pragma unroll 2
  for (int i = 0; i < 8; ++i) {
    int idx = i * 256 + tid;
    int row = idx >> 4, ch = idx & 15;
    int grow = m0 + row;
    if (grow >= NN) grow = NN - 1;
    *(bf16x8*)&lds[row * LW + ch * 8] =
        *(const bf16x8*)(h16 + (size_t)grow * HID + ch * 8);
  }
  __syncthreads();

  const f32x4 zero = {0.f, 0.f, 0.f, 0.f};
#pragma unroll
  for (int rt = 0; rt < 2; ++rt) {
    bf16x8 af[4];
#pragma unroll
    for (int s = 0; s < 4; ++s)
      af[s] = *(const bf16x8*)&lds[(wid * 32 + rt * 16 + j) * LW + 32 * s + 8 * g];
    f32x4 acc[3] = {zero, zero, zero};
#pragma unroll
    for (int s = 0; s < 4; ++s)
#pragma unroll
      for (int c = 0; c < 3; ++c)
        acc[c] = __builtin_amdgcn_mfma_f32_16x16x32_bf16(af[s], bfrag[c][s], acc[c], 0, 0, 0);

#pragma unroll
    for (int i = 0; i < 4; ++i) {
      const int rr = m0 + wid * 32 + rt * 16 + 4 * g + i;
      float z0 = acc[0][i] + bb[0];
      float z1 = acc[1][i] + bb[1];
      float z2 = acc[2][i] + bb[2];
      float m = fmaxf(fmaxf(z0, z1), z2);
      m = fmaxf(m, __shfl_xor(m, 1));
      m = fmaxf(m, __shfl_xor(m, 2));
      m = fmaxf(m, __shfl_xor(m, 4));
      m = fmaxf(m, __shfl_xor(m, 8));
      float sum = __expf(z0 - m) + __expf(z1 - m) + __expf(z2 - m);
      sum += __shfl_xor(sum, 1);
      sum += __shfl_xor(sum, 2);
      sum += __shfl_xor(sum, 4);
      sum += __shfl_xor(sum, 8);
      float ls = m + logf(sum);
      if (rr < NN) {
        out[(size_t)rr * OUTC + j] = z0 - ls;
        out[(size_t)rr * OUTC + 16 + j] = z1 - ls;
        if (j < 8) out[(size_t)rr * OUTC + 32 + j] = z2 - ls;
      }
    }
  }
}

// ---------------- aggregation: hc16 = bf16(0.5*(A_hat @ h16) + 0.5*x016) ----------------
static __global__ __launch_bounds__(256) void k_agg(
    const unsigned short* __restrict__ h16, const unsigned short* __restrict__ x016,
    const float* __restrict__ dinv, const int* __restrict__ offs,
    const int2* __restrict__ edata, unsigned short* __restrict__ hc16) {
  int wid = threadIdx.x >> 6;
  int n = blockIdx.x * 4 + wid;
  if (n >= NN) return;
  int lane = threadIdx.x & 63;
  int cg = (lane & 7) * 16;
  int slot = lane >> 3;

  int b = offs[n], e = offs[n + 1];
  float acc[16];
#pragma unroll
  for (int q = 0; q < 16; ++q) acc[q] = 0.f;

#define ACC16(VA, VB, W)                                               \
  {                                                                    \
    acc[0]  = fmaf((W), bflo((VA).x), acc[0]);                         \
    acc[1]  = fmaf((W), bfhi((VA).x), acc[1]);                         \
    acc[2]  = fmaf((W), bflo((VA).y), acc[2]);                         \
    acc[3]  = fmaf((W), bfhi((VA).y), acc[3]);                         \
    acc[4]  = fmaf((W), bflo((VA).z), acc[4]);                         \
    acc[5]  = fmaf((W), bfhi((VA).z), acc[5]);                         \
    acc[6]  = fmaf((W), bflo((VA).w), acc[6]);                         \
    acc[7]  = fmaf((W), bfhi((VA).w), acc[7]);                         \
    acc[8]  = fmaf((W), bflo((VB).x), acc[8]);                         \
    acc[9]  = fmaf((W), bfhi((VB).x), acc[9]);                         \
    acc[10] = fmaf((W), bflo((VB).y), acc[10]);                        \
    acc[11] = fmaf((W), bfhi((VB).y), acc[11]);                        \
    acc[12] = fmaf((W), bflo((VB).z), acc[12]);                        \
    acc[13] = fmaf((W), bfhi((VB).z), acc[13]);                        \
    acc[14] = fmaf((W), bflo((VB).w), acc[14]);                        \
    acc[15] = fmaf((W), bfhi((VB).w), acc[15]);                        \
  }

  if (slot == 0) {
    float dn = dinv[n];
    const unsigned short* p = h16 + (size_t)n * HID + cg;
    uint4 va = *(const uint4*)p, vb = *(const uint4*)(p + 8);
    ACC16(va, vb, dn * dn);
  }
  int i = b + slot;
  for (; i + 8 < e; i += 16) {
    int2 e0 = edata[i], e1 = edata[i + 8];
    const unsigned short* p0 = h16 + (size_t)e0.x * HID + cg;
    const unsigned short* p1 = h16 + (size_t)e1.x * HID + cg;
    uint4 a0 = *(const uint4*)p0, b0 = *(const uint4*)(p0 + 8);
    uint4 a1 = *(const uint4*)p1, b1 = *(const uint4*)(p1 + 8);
    float w0 = __int_as_float(e0.y), w1 = __int_as_float(e1.y);
    ACC16(a0, b0, w0);
    ACC16(a1, b1, w1);
  }
  if (i < e) {
    int2 e0 = edata[i];
    const unsigned short* p0 = h16 + (size_t)e0.x * HID + cg;
    uint4 a0 = *(const uint4*)p0, b0 = *(const uint4*)(p0 + 8);
    ACC16(a0, b0, __int_as_float(e0.y));
  }
#undef ACC16

#pragma unroll
  for (int q = 0; q < 16; ++q) {
    acc[q] += __shfl_xor(acc[q], 8);
    acc[q] += __shfl_xor(acc[q], 16);
    acc[q] += __shfl_xor(acc[q], 32);
  }

  if (lane < 8) {
    size_t nc = (size_t)n * HID + cg;
    const uint4 xa = *(const uint4*)(x016 + nc);
    const uint4 xb = *(const uint4*)(x016 + nc + 8);
    float o[16];
    o[0]  = 0.5f * acc[0]  + 0.5f * bflo(xa.x);
    o[1]  = 0.5f * acc[1]  + 0.5f * bfhi(xa.x);
    o[2]  = 0.5f * acc[2]  + 0.5f * bflo(xa.y);
    o[3]  = 0.5f * acc[3]  + 0.5f * bfhi(xa.y);
    o[4]  = 0.5f * acc[4]  + 0.5f * bflo(xa.z);
    o[5]  = 0.5f * acc[5]  + 0.5f * bfhi(xa.z);
    o[6]  = 0.5f * acc[6]  + 0.5f * bflo(xa.w);
    o[7]  = 0.5f * acc[7]  + 0.5f * bfhi(xa.w);
    o[8]  = 0.5f * acc[8]  + 0.5f * bflo(xb.x);
    o[9]  = 0.5f * acc[9]  + 0.5f * bfhi(xb.x);
    o[10] = 0.5f * acc[10] + 0.5f * bflo(xb.y);
    o[11] = 0.5f * acc[11] + 0.5f * bfhi(xb.y);
    o[12] = 0.5f * acc[12] + 0.5f * bflo(xb.z);
    o[13] = 0.5f * acc[13] + 0.5f * bfhi(xb.z);
    o[14] = 0.5f * acc[14] + 0.5f * bflo(xb.w);
    o[15] = 0.5f * acc[15] + 0.5f * bfhi(xb.w);
    unsigned short q[16];
#pragma unroll
    for (int t = 0; t < 16; ++t) q[t] = f2bf(o[t]);
    *(uint4*)(hc16 + nc) = *(const uint4*)&q[0];
    *(uint4*)(hc16 + nc + 8) = *(const uint4*)&q[8];
  }
}

// ---------------- host ----------------
extern "C" void kernel_launch(void* const* d_in, const int* in_sizes, int n_in,
                              void* d_out, int out_size, void* d_ws, size_t ws_size,
                              hipStream_t stream) {
  const float* x  = (const float*)d_in[0];
  const int*   ei = (const int*)d_in[1];
  const float* w1 = (const float*)d_in[2];
  const float* b1 = (const float*)d_in[3];
  const float* cw = (const float*)d_in[4];
  const float* w2 = (const float*)d_in[5];
  const float* b2 = (const float*)d_in[6];
  float* out = (float*)d_out;

  char* ws = (char*)d_ws;
  size_t o = 0;
  auto carve = [&](size_t bytes) {
    void* p = ws + o;
    o = (o + bytes + 255) & ~(size_t)255;
    return p;
  };
  float* dinv   = (float*)carve((size_t)NN * 4);
  int*   offs   = (int*)carve((size_t)(NN + 1) * 4);
  int*   cursor = (int*)carve((size_t)NN * 4);
  int*   bcnt   = (int*)carve((size_t)NBUCK * 4);
  int*   boffs  = (int*)carve((size_t)(NBUCK + 1) * 4);
  int*   bcur   = (int*)carve((size_t)NBUCK * 4);
  int2*  stage  = (int2*)carve((size_t)NE * 8);
  int2*  edata  = (int2*)carve((size_t)NE * 8);
  unsigned short* x016  = (unsigned short*)carve((size_t)NN * HID * 2);
  unsigned short* hb16  = (unsigned short*)carve((size_t)NN * HID * 2);
  unsigned short* hcb16 = (unsigned short*)carve((size_t)NN * HID * 2);
  unsigned short* wt1   = (unsigned short*)carve((size_t)INCH * HID * 2);
  unsigned short* wtl   = (unsigned short*)carve((size_t)NLAYERS * HID * HID * 2);
  unsigned short* wt2   = (unsigned short*)carve((size_t)48 * HID * 2);
  (void)ws_size; (void)in_sizes; (void)n_in; (void)out_size;

  const int TB = 256;
  const int gEB = (NE + EPB - 1) / EPB;  // 391

  k_zerob<<<(NBUCK + 255) / 256, TB, 0, stream>>>(bcnt);
  k_bhist<<<gEB, TB, 0, stream>>>(ei, bcnt);
  k_bscan<<<1, 512, 0, stream>>>(bcnt, boffs, bcur, offs);
  k_sortA<<<gEB, TB, 0, stream>>>(ei, bcur, stage);
  k_degs<<<NBUCK, TB, 0, stream>>>(stage, boffs, offs, dinv, cursor);
  k_passB2<<<NBUCK, TB, 0, stream>>>(stage, boffs, offs, dinv, cursor, edata);

  k_cvtw<<<(INCH * HID + 255) / 256, 256, 0, stream>>>(w1, wt1, INCH);
  k_cvtw8<<<(NLAYERS * HID * HID + 255) / 256, 256, 0, stream>>>(cw, wtl);
  k_cvtw2<<<(48 * HID + 255) / 256, 256, 0, stream>>>(w2, wt2);

  const int gG = (NN + 127) / 128;  // 782
  k_lin1<<<gG, 256, 0, stream>>>(x, wt1, b1, x016, NN);

  const unsigned short* hin = x016;
  const int gA = (NN + 3) / 4;  // 25000
  for (int l = 0; l < NLAYERS; ++l) {
    k_agg<<<gA, 256, 0, stream>>>(hin, x016, dinv, offs, edata, hcb16);
    k_mgemm1<<<gG, 256, 0, stream>>>(hcb16, wtl + (size_t)l * HID * HID, hb16, NN);
    hin = hb16;
  }
  k_mlin2<<<gG, 256, 0, stream>>>(hb16, wt2, b2, out);
}

// Round 10
// 780.734 us; speedup vs baseline: 3.7816x; 1.0273x over previous
//
#include <hip/hip_runtime.h>
#include <math.h>

#define NN 100000
#define NE 1600000
#define HID 128
#define INCH 256
#define OUTC 40
#define NLAYERS 8
#define NBUCK 391   // ceil(NN/256)
#define EPB 4096
#define CAP 6144
#define LW 136      // LDS row stride in ushorts (272 B)

typedef __attribute__((ext_vector_type(8))) short bf16x8;
typedef __attribute__((ext_vector_type(4))) float f32x4;

static __device__ inline unsigned short f2bf(float f) {
  unsigned u = __float_as_uint(f);
  unsigned r = (u + 0x7fff + ((u >> 16) & 1)) >> 16;
  return (unsigned short)r;
}
static __device__ inline float bflo(unsigned u) { return __uint_as_float(u << 16); }
static __device__ inline float bfhi(unsigned u) { return __uint_as_float(u & 0xffff0000u); }

// ---------------- preprocessing (atomic-light counting sort) ----------------

static __global__ void k_zerob(int* __restrict__ bcnt) {
  int i = blockIdx.x * 256 + threadIdx.x;
  if (i < NBUCK) bcnt[i] = 0;
}

static __global__ __launch_bounds__(256) void k_bhist(const int* __restrict__ ei,
                                                      int* __restrict__ bcnt) {
  __shared__ int lh[NBUCK + 1];
  int t = threadIdx.x;
  for (int i = t; i <= NBUCK; i += 256) lh[i] = 0;
  __syncthreads();
  int e0 = blockIdx.x * EPB;
  for (int k = t; k < EPB; k += 256) {
    int e = e0 + k;
    if (e < NE) atomicAdd(&lh[ei[NE + e] >> 8], 1);
  }
  __syncthreads();
  for (int i = t; i < NBUCK; i += 256)
    if (lh[i]) atomicAdd(&bcnt[i], lh[i]);
}

static __global__ void k_bscan(const int* __restrict__ bcnt, int* __restrict__ boffs,
                               int* __restrict__ bcur, int* __restrict__ offs) {
  __shared__ int sd[512];
  int t = threadIdx.x;
  sd[t] = (t < NBUCK) ? bcnt[t] : 0;
  __syncthreads();
  for (int d = 1; d < 512; d <<= 1) {
    int v = (t >= d) ? sd[t - d] : 0;
    __syncthreads();
    sd[t] += v;
    __syncthreads();
  }
  if (t < NBUCK) {
    boffs[t + 1] = sd[t];
    bcur[t] = sd[t] - bcnt[t];
  }
  if (t == 0) { boffs[0] = 0; offs[NN] = NE; }
}

static __global__ __launch_bounds__(256) void k_sortA(const int* __restrict__ ei,
                                                      int* __restrict__ bcur,
                                                      int2* __restrict__ stage) {
  __shared__ int lsrc[EPB], ldst[EPB];
  __shared__ int lh[NBUCK + 1], lbase[NBUCK + 1], lcur[NBUCK + 1];
  int t = threadIdx.x;
  int e0 = blockIdx.x * EPB;
  for (int k = t; k < EPB; k += 256) {
    int e = e0 + k;
    lsrc[k] = (e < NE) ? ei[e] : -1;
    ldst[k] = (e < NE) ? ei[NE + e] : -1;
  }
  for (int i = t; i <= NBUCK; i += 256) lh[i] = 0;
  __syncthreads();
  for (int k = t; k < EPB; k += 256)
    if (ldst[k] >= 0) atomicAdd(&lh[ldst[k] >> 8], 1);
  __syncthreads();
  for (int i = t; i < NBUCK; i += 256) {
    int c = lh[i];
    lbase[i] = c ? atomicAdd(&bcur[i], c) : 0;
    lcur[i] = 0;
  }
  __syncthreads();
  for (int k = t; k < EPB; k += 256) {
    int d = ldst[k];
    if (d >= 0) {
      int bu = d >> 8;
      int r = atomicAdd(&lcur[bu], 1);
      stage[lbase[bu] + r] = make_int2(lsrc[k], d);
    }
  }
}

static __global__ __launch_bounds__(256) void k_degs(
    const int2* __restrict__ stage, const int* __restrict__ boffs,
    int* __restrict__ offs, float* __restrict__ dinv, int* __restrict__ cursor) {
  __shared__ int lcnt[256];
  __shared__ int sd[256];
  int b = blockIdx.x, t = threadIdx.x;
  int sb = boffs[b], se = boffs[b + 1];
  int cntb = se - sb;
  int nb0 = b << 8;
  lcnt[t] = 0;
  __syncthreads();
  for (int k = t; k < cntb; k += 256) atomicAdd(&lcnt[stage[sb + k].y - nb0], 1);
  __syncthreads();
  int v = lcnt[t];
  sd[t] = v;
  __syncthreads();
  for (int d = 1; d < 256; d <<= 1) {
    int u = (t >= d) ? sd[t - d] : 0;
    __syncthreads();
    sd[t] += u;
    __syncthreads();
  }
  int n = nb0 + t;
  if (n < NN) {
    int o = sb + sd[t] - v;
    offs[n] = o;
    cursor[n] = o;
    dinv[n] = rsqrtf((float)(v + 1));
  }
}

static __global__ __launch_bounds__(256) void k_passB2(
    const int2* __restrict__ stage, const int* __restrict__ boffs,
    const int* __restrict__ offs, const float* __restrict__ dinv,
    int* __restrict__ cursor, int2* __restrict__ edata) {
  __shared__ int2 lbuf[CAP];
  __shared__ int lcur[256];
  int b = blockIdx.x, t = threadIdx.x;
  int sb = boffs[b], se = boffs[b + 1];
  int cntb = se - sb;
  int nb0 = b << 8;
  if (cntb <= CAP) {
    if (nb0 + t < NN) lcur[t] = offs[nb0 + t] - sb;
    __syncthreads();
    for (int k = t; k < cntb; k += 256) {
      int2 sd_ = stage[sb + k];
      float w = dinv[sd_.x] * dinv[sd_.y];
      int p = atomicAdd(&lcur[sd_.y - nb0], 1);
      lbuf[p] = make_int2(sd_.x, __float_as_int(w));
    }
    __syncthreads();
    for (int k = t; k < cntb; k += 256) edata[sb + k] = lbuf[k];
  } else {
    for (int k = t; k < cntb; k += 256) {
      int2 sd_ = stage[sb + k];
      float w = dinv[sd_.x] * dinv[sd_.y];
      int p = atomicAdd(&cursor[sd_.y], 1);
      edata[p] = make_int2(sd_.x, __float_as_int(w));
    }
  }
}

// ---------------- weight conversion ----------------
static __global__ void k_cvtw(const float* __restrict__ W, unsigned short* __restrict__ Wt,
                              int K) {
  int idx = blockIdx.x * 256 + threadIdx.x;
  if (idx < K * HID) {
    int k = idx >> 7, n = idx & 127;
    Wt[(size_t)n * K + k] = f2bf(W[idx]);
  }
}

// Folded layer weights: W'_l = beta_l * W_l + (1-beta_l) * I, transposed [n][k]
static __global__ void k_cvtw8(const float* __restrict__ W, unsigned short* __restrict__ Wt) {
  int idx = blockIdx.x * 256 + threadIdx.x;
  if (idx < NLAYERS * HID * HID) {
    int l = idx >> 14, rem = idx & 16383;
    int k = rem >> 7, n = rem & 127;
    float beta = logf(1.0f / (float)(l + 1) + 1.0f);
    float v = beta * W[idx];
    if (k == n) v += 1.0f - beta;
    Wt[(size_t)l * HID * HID + n * HID + k] = f2bf(v);
  }
}

static __global__ void k_cvtw2(const float* __restrict__ W2, unsigned short* __restrict__ Wt2) {
  int idx = blockIdx.x * 256 + threadIdx.x;
  if (idx < 48 * HID) {
    int n = idx >> 7, k = idx & 127;
    Wt2[idx] = (n < OUTC) ? f2bf(W2[(size_t)k * OUTC + n]) : 0;
  }
}

// ---------------- lin1: C16[M x 128] = bf16(relu(A32[M x 256] @ W + bias)) ----------------
__global__ __launch_bounds__(256, 3) void k_lin1(
    const float* __restrict__ A32, const unsigned short* __restrict__ Wt16,
    const float* __restrict__ bias, unsigned short* __restrict__ C16, int M) {
  __shared__ unsigned short lds[128 * LW];
  const int tid = threadIdx.x;
  const int lane = tid & 63;
  const int wid = tid >> 6;
  const int j = lane & 15, g = lane >> 4;
  const int rowhalf = (wid >> 1) * 64;
  const int colbase = (wid & 1) * 64;
  const int m0 = blockIdx.x * 128;

  f32x4 acc[4][4];
  const f32x4 zero = {0.f, 0.f, 0.f, 0.f};
#pragma unroll
  for (int rt = 0; rt < 4; ++rt)
#pragma unroll
    for (int c = 0; c < 4; ++c) acc[rt][c] = zero;

#pragma unroll 1
  for (int kc = 0; kc < 2; ++kc) {
    bf16x8 bfrag[4][4];
#pragma unroll
    for (int c = 0; c < 4; ++c)
#pragma unroll
      for (int s = 0; s < 4; ++s)
        bfrag[c][s] = *(const bf16x8*)(Wt16 + (size_t)(colbase + 16 * c + j) * INCH +
                                       kc * 128 + 32 * s + 8 * g);
    __syncthreads();
#pragma unroll 2
    for (int i = 0; i < 8; ++i) {
      int idx = i * 256 + tid;
      int row = idx >> 4, ch = idx & 15;
      int grow = m0 + row;
      if (grow >= M) grow = M - 1;
      const float* p = A32 + (size_t)grow * INCH + kc * 128 + ch * 8;
      float4 u0 = *(const float4*)p;
      float4 u1 = *(const float4*)(p + 4);
      bf16x8 v;
      v[0] = (short)f2bf(u0.x); v[1] = (short)f2bf(u0.y);
      v[2] = (short)f2bf(u0.z); v[3] = (short)f2bf(u0.w);
      v[4] = (short)f2bf(u1.x); v[5] = (short)f2bf(u1.y);
      v[6] = (short)f2bf(u1.z); v[7] = (short)f2bf(u1.w);
      *(bf16x8*)&lds[row * LW + ch * 8] = v;
    }
    __syncthreads();
#pragma unroll
    for (int rt = 0; rt < 4; ++rt) {
      bf16x8 af[4];
#pragma unroll
      for (int s = 0; s < 4; ++s)
        af[s] = *(const bf16x8*)&lds[(rowhalf + rt * 16 + j) * LW + 32 * s + 8 * g];
#pragma unroll
      for (int s = 0; s < 4; ++s)
#pragma unroll
        for (int c = 0; c < 4; ++c)
          acc[rt][c] =
              __builtin_amdgcn_mfma_f32_16x16x32_bf16(af[s], bfrag[c][s], acc[rt][c], 0, 0, 0);
    }
  }

#pragma unroll
  for (int rt = 0; rt < 4; ++rt)
#pragma unroll
    for (int i = 0; i < 4; ++i) {
      const int rr = m0 + rowhalf + rt * 16 + 4 * g + i;
      if (rr >= M) continue;
#pragma unroll
      for (int c = 0; c < 4; ++c) {
        const int col = colbase + 16 * c + j;
        float z = fmaxf(acc[rt][c][i] + bias[col], 0.f);
        C16[(size_t)rr * HID + col] = f2bf(z);
      }
    }
}

// ---------------- fused layer: agg (gather) + GEMM ----------------
// Block = 64 nodes. Phase 1: hc = 0.5*(A_hat@h)+0.5*x0 -> LDS bf16 tile.
//   4 lanes/node x 32 ch, acc in regs, no cross-lane reduce.
// Phase 2: hb = relu(hc @ W') via MFMA (skip folded into W'), tile 64x128.
#define ACC8(V, O, W)                                       \
  acc[(O) + 0] = fmaf((W), bflo((V).x), acc[(O) + 0]);      \
  acc[(O) + 1] = fmaf((W), bfhi((V).x), acc[(O) + 1]);      \
  acc[(O) + 2] = fmaf((W), bflo((V).y), acc[(O) + 2]);      \
  acc[(O) + 3] = fmaf((W), bfhi((V).y), acc[(O) + 3]);      \
  acc[(O) + 4] = fmaf((W), bflo((V).z), acc[(O) + 4]);      \
  acc[(O) + 5] = fmaf((W), bfhi((V).z), acc[(O) + 5]);      \
  acc[(O) + 6] = fmaf((W), bflo((V).w), acc[(O) + 6]);      \
  acc[(O) + 7] = fmaf((W), bfhi((V).w), acc[(O) + 7]);

#define EDGE4(P, W)                                          \
  {                                                          \
    uint4 v0 = *(const uint4*)(P);                           \
    uint4 v1 = *(const uint4*)((P) + 8);                     \
    uint4 v2 = *(const uint4*)((P) + 16);                    \
    uint4 v3 = *(const uint4*)((P) + 24);                    \
    ACC8(v0, 0, W) ACC8(v1, 8, W) ACC8(v2, 16, W) ACC8(v3, 24, W) \
  }

__global__ __launch_bounds__(256) void k_fused(
    const unsigned short* __restrict__ h16, const unsigned short* __restrict__ x016,
    const float* __restrict__ dinv, const int* __restrict__ offs,
    const int2* __restrict__ edata, const unsigned short* __restrict__ Wt16,
    unsigned short* __restrict__ C16, int M) {
  __shared__ unsigned short lds[64 * LW];
  const int tid = threadIdx.x;
  const int m0 = blockIdx.x * 64;
  const int node = m0 + (tid >> 2);
  const int cq = (tid & 3) * 32;

  float acc[32];
#pragma unroll
  for (int q = 0; q < 32; ++q) acc[q] = 0.f;

  unsigned short q16[32];
  if (node < M) {
    int b = offs[node], e = offs[node + 1];
    float dn = dinv[node];
    {  // self loop
      const unsigned short* p = h16 + (size_t)node * HID + cq;
      EDGE4(p, dn * dn);
    }
    int i = b;
    for (; i + 1 < e; i += 2) {
      int2 e0 = edata[i], e1 = edata[i + 1];
      const unsigned short* p0 = h16 + (size_t)e0.x * HID + cq;
      const unsigned short* p1 = h16 + (size_t)e1.x * HID + cq;
      float w0 = __int_as_float(e0.y), w1 = __int_as_float(e1.y);
      EDGE4(p0, w0);
      EDGE4(p1, w1);
    }
    if (i < e) {
      int2 e0 = edata[i];
      EDGE4(h16 + (size_t)e0.x * HID + cq, __int_as_float(e0.y));
    }
    // hc = 0.5*acc + 0.5*x0 -> bf16
    const unsigned short* px = x016 + (size_t)node * HID + cq;
    uint4 xa = *(const uint4*)px, xb = *(const uint4*)(px + 8);
    uint4 xc = *(const uint4*)(px + 16), xd = *(const uint4*)(px + 24);
    float xo[32];
#define UNP8(V, O)                                                     \
    xo[(O) + 0] = bflo((V).x); xo[(O) + 1] = bfhi((V).x);              \
    xo[(O) + 2] = bflo((V).y); xo[(O) + 3] = bfhi((V).y);              \
    xo[(O) + 4] = bflo((V).z); xo[(O) + 5] = bfhi((V).z);              \
    xo[(O) + 6] = bflo((V).w); xo[(O) + 7] = bfhi((V).w);
    UNP8(xa, 0) UNP8(xb, 8) UNP8(xc, 16) UNP8(xd, 24)
#undef UNP8
#pragma unroll
    for (int q = 0; q < 32; ++q) q16[q] = f2bf(0.5f * acc[q] + 0.5f * xo[q]);
  } else {
#pragma unroll
    for (int q = 0; q < 32; ++q) q16[q] = 0;
  }
  {
    unsigned short* lrow = &lds[(tid >> 2) * LW + cq];
    *(uint4*)(lrow) = *(const uint4*)&q16[0];
    *(uint4*)(lrow + 8) = *(const uint4*)&q16[8];
    *(uint4*)(lrow + 16) = *(const uint4*)&q16[16];
    *(uint4*)(lrow + 24) = *(const uint4*)&q16[24];
  }
  __syncthreads();

  // phase 2: GEMM 64x128
  const int lane = tid & 63;
  const int wid = tid >> 6;
  const int rq = (wid >> 1) * 32;
  const int colbase = (wid & 1) * 64;
  const int j = lane & 15, g = lane >> 4;

  bf16x8 bfrag[4][4];
#pragma unroll
  for (int c = 0; c < 4; ++c)
#pragma unroll
    for (int s = 0; s < 4; ++s)
      bfrag[c][s] =
          *(const bf16x8*)(Wt16 + (size_t)(colbase + 16 * c + j) * HID + 32 * s + 8 * g);

  const f32x4 zero = {0.f, 0.f, 0.f, 0.f};
#pragma unroll
  for (int rt = 0; rt < 2; ++rt) {
    bf16x8 af[4];
#pragma unroll
    for (int s = 0; s < 4; ++s)
      af[s] = *(const bf16x8*)&lds[(rq + rt * 16 + j) * LW + 32 * s + 8 * g];
    f32x4 a2[4] = {zero, zero, zero, zero};
#pragma unroll
    for (int s = 0; s < 4; ++s)
#pragma unroll
      for (int c = 0; c < 4; ++c)
        a2[c] = __builtin_amdgcn_mfma_f32_16x16x32_bf16(af[s], bfrag[c][s], a2[c], 0, 0, 0);
#pragma unroll
    for (int i = 0; i < 4; ++i) {
      const int rr = m0 + rq + rt * 16 + 4 * g + i;
      if (rr >= M) continue;
#pragma unroll
      for (int c = 0; c < 4; ++c) {
        const int col = colbase + 16 * c + j;
        C16[(size_t)rr * HID + col] = f2bf(fmaxf(a2[c][i], 0.f));
      }
    }
  }
}

// ---------------- fused lin2 + log_softmax via MFMA ----------------
static __global__ __launch_bounds__(256, 3) void k_mlin2(
    const unsigned short* __restrict__ h16, const unsigned short* __restrict__ Wt2,
    const float* __restrict__ b2, float* __restrict__ out) {
  __shared__ unsigned short lds[128 * LW];
  const int tid = threadIdx.x;
  const int lane = tid & 63;
  const int wid = tid >> 6;
  const int j = lane & 15, g = lane >> 4;
  const int m0 = blockIdx.x * 128;

  bf16x8 bfrag[3][4];
#pragma unroll
  for (int c = 0; c < 3; ++c)
#pragma unroll
    for (int s = 0; s < 4; ++s)
      bfrag[c][s] = *(const bf16x8*)(Wt2 + (size_t)(16 * c + j) * HID + 32 * s + 8 * g);

  float bb[3];
#pragma unroll
  for (int c = 0; c < 3; ++c) {
    int col = 16 * c + j;
    bb[c] = (col < OUTC) ? b2[col] : -1e30f;
  }

#pragma unroll 2
  for (int i = 0; i < 8; ++i) {
    int idx = i * 256 + tid;
    int row = idx >> 4, ch = idx & 15;
    int grow = m0 + row;
    if (grow >= NN) grow = NN - 1;
    *(bf16x8*)&lds[row * LW + ch * 8] =
        *(const bf16x8*)(h16 + (size_t)grow * HID + ch * 8);
  }
  __syncthreads();

  const f32x4 zero = {0.f, 0.f, 0.f, 0.f};
#pragma unroll
  for (int rt = 0; rt < 2; ++rt) {
    bf16x8 af[4];
#pragma unroll
    for (int s = 0; s < 4; ++s)
      af[s] = *(const bf16x8*)&lds[(wid * 32 + rt * 16 + j) * LW + 32 * s + 8 * g];
    f32x4 acc[3] = {zero, zero, zero};
#pragma unroll
    for (int s = 0; s < 4; ++s)
#pragma unroll
      for (int c = 0; c < 3; ++c)
        acc[c] = __builtin_amdgcn_mfma_f32_16x16x32_bf16(af[s], bfrag[c][s], acc[c], 0, 0, 0);

#pragma unroll
    for (int i = 0; i < 4; ++i) {
      const int rr = m0 + wid * 32 + rt * 16 + 4 * g + i;
      float z0 = acc[0][i] + bb[0];
      float z1 = acc[1][i] + bb[1];
      float z2 = acc[2][i] + bb[2];
      float m = fmaxf(fmaxf(z0, z1), z2);
      m = fmaxf(m, __shfl_xor(m, 1));
      m = fmaxf(m, __shfl_xor(m, 2));
      m = fmaxf(m, __shfl_xor(m, 4));
      m = fmaxf(m, __shfl_xor(m, 8));
      float sum = __expf(z0 - m) + __expf(z1 - m) + __expf(z2 - m);
      sum += __shfl_xor(sum, 1);
      sum += __shfl_xor(sum, 2);
      sum += __shfl_xor(sum, 4);
      sum += __shfl_xor(sum, 8);
      float ls = m + logf(sum);
      if (rr < NN) {
        out[(size_t)rr * OUTC + j] = z0 - ls;
        out[(size_t)rr * OUTC + 16 + j] = z1 - ls;
        if (j < 8) out[(size_t)rr * OUTC + 32 + j] = z2 - ls;
      }
    }
  }
}

// ---------------- host ----------------
extern "C" void kernel_launch(void* const* d_in, const int* in_sizes, int n_in,
                              void* d_out, int out_size, void* d_ws, size_t ws_size,
                              hipStream_t stream) {
  const float* x  = (const float*)d_in[0];
  const int*   ei = (const int*)d_in[1];
  const float* w1 = (const float*)d_in[2];
  const float* b1 = (const float*)d_in[3];
  const float* cw = (const float*)d_in[4];
  const float* w2 = (const float*)d_in[5];
  const float* b2 = (const float*)d_in[6];
  float* out = (float*)d_out;

  char* ws = (char*)d_ws;
  size_t o = 0;
  auto carve = [&](size_t bytes) {
    void* p = ws + o;
    o = (o + bytes + 255) & ~(size_t)255;
    return p;
  };
  float* dinv   = (float*)carve((size_t)NN * 4);
  int*   offs   = (int*)carve((size_t)(NN + 1) * 4);
  int*   cursor = (int*)carve((size_t)NN * 4);
  int*   bcnt   = (int*)carve((size_t)NBUCK * 4);
  int*   boffs  = (int*)carve((size_t)(NBUCK + 1) * 4);
  int*   bcur   = (int*)carve((size_t)NBUCK * 4);
  int2*  stage  = (int2*)carve((size_t)NE * 8);
  int2*  edata  = (int2*)carve((size_t)NE * 8);
  unsigned short* x016 = (unsigned short*)carve((size_t)NN * HID * 2);
  unsigned short* hbA  = (unsigned short*)carve((size_t)NN * HID * 2);
  unsigned short* hbB  = (unsigned short*)carve((size_t)NN * HID * 2);
  unsigned short* wt1  = (unsigned short*)carve((size_t)INCH * HID * 2);
  unsigned short* wtl  = (unsigned short*)carve((size_t)NLAYERS * HID * HID * 2);
  unsigned short* wt2  = (unsigned short*)carve((size_t)48 * HID * 2);
  (void)ws_size; (void)in_sizes; (void)n_in; (void)out_size;

  const int TB = 256;
  const int gEB = (NE + EPB - 1) / EPB;  // 391

  k_zerob<<<(NBUCK + 255) / 256, TB, 0, stream>>>(bcnt);
  k_bhist<<<gEB, TB, 0, stream>>>(ei, bcnt);
  k_bscan<<<1, 512, 0, stream>>>(bcnt, boffs, bcur, offs);
  k_sortA<<<gEB, TB, 0, stream>>>(ei, bcur, stage);
  k_degs<<<NBUCK, TB, 0, stream>>>(stage, boffs, offs, dinv, cursor);
  k_passB2<<<NBUCK, TB, 0, stream>>>(stage, boffs, offs, dinv, cursor, edata);

  k_cvtw<<<(INCH * HID + 255) / 256, 256, 0, stream>>>(w1, wt1, INCH);
  k_cvtw8<<<(NLAYERS * HID * HID + 255) / 256, 256, 0, stream>>>(cw, wtl);
  k_cvtw2<<<(48 * HID + 255) / 256, 256, 0, stream>>>(w2, wt2);

  k_lin1<<<(NN + 127) / 128, 256, 0, stream>>>(x, wt1, b1, x016, NN);

  const int gF = (NN + 63) / 64;  // 1563
  const unsigned short* hin = x016;
  unsigned short* hout = hbA;
  for (int l = 0; l < NLAYERS; ++l) {
    k_fused<<<gF, 256, 0, stream>>>(hin, x016, dinv, offs, edata,
                                    wtl + (size_t)l * HID * HID, hout, NN);
    hin = hout;
    hout = (hout == hbA) ? hbB : hbA;
  }
  k_mlin2<<<(NN + 127) / 128, 256, 0, stream>>>(hin, wt2, b2, out);
}